// Round 5
// baseline (3167.056 us; speedup 1.0000x reference)
//
#include <hip/hip_runtime.h>

typedef _Float16 f16;
typedef _Float16 f16x8 __attribute__((ext_vector_type(8)));
typedef float f32x4 __attribute__((ext_vector_type(4)));

#define N_NODES 50000
#define N_EDGES 600000
#define G_GRAPHS 128
#define H 128
#define NP 50176              // 196*256, padded node count for scan
#define NTILES 1563           // ceil(50000/32)

// ---------------------------------------------------------------------------
// f0 = relu(node_f @ W_in + b_in)  -> fh (f16)
// ---------------------------------------------------------------------------
__global__ void k_f0(const float* __restrict__ node_f, const float* __restrict__ W_in,
                     const float* __restrict__ b_in, f16* __restrict__ fh)
{
    __shared__ float sW[32 * 128];
    __shared__ float sx[8][32];
    const int tid = threadIdx.x;     // 128 threads
    const int base = blockIdx.x * 8;
    for (int i = tid; i < 32 * 128; i += 128) sW[i] = W_in[i];
    for (int i = tid; i < 8 * 32; i += 128) {
        int u = i >> 5, k = i & 31;
        int n = base + u;
        sx[u][k] = (n < N_NODES) ? node_f[(size_t)n * 32 + k] : 0.0f;
    }
    __syncthreads();
    const float bj = b_in[tid];
    #pragma unroll
    for (int u = 0; u < 8; ++u) {
        int n = base + u;
        if (n >= N_NODES) break;
        float acc = bj;
        #pragma unroll
        for (int k = 0; k < 32; ++k) acc = fmaf(sx[u][k], sW[k * 128 + tid], acc);
        fh[(size_t)n * H + tid] = (f16)fmaxf(acc, 0.0f);
    }
}

// ---------------------------------------------------------------------------
// CSR build: histogram, scan (3 kernels), idx scatter, sequential gather
// ---------------------------------------------------------------------------
__global__ void k_hist(const int* __restrict__ dst, int* __restrict__ cnt)
{
    int e = blockIdx.x * 256 + threadIdx.x;
    if (e < N_EDGES) atomicAdd(&cnt[dst[e]], 1);
}

__global__ void k_scanA(const int* __restrict__ cnt, int* __restrict__ rowptr,
                        int* __restrict__ bsum)
{
    __shared__ int s[256];
    const int t = threadIdx.x;
    const int i = blockIdx.x * 256 + t;
    int v = cnt[i];
    s[t] = v;
    __syncthreads();
    #pragma unroll
    for (int off = 1; off < 256; off <<= 1) {
        int x = (t >= off) ? s[t - off] : 0;
        __syncthreads();
        s[t] += x;
        __syncthreads();
    }
    rowptr[i] = s[t] - v;            // exclusive, pre-offset
    if (t == 255) bsum[blockIdx.x] = s[255];
}

__global__ void k_scanB(const int* __restrict__ bsum, int* __restrict__ boff)
{
    __shared__ int s[256];
    const int t = threadIdx.x;
    int v = (t < 196) ? bsum[t] : 0;
    s[t] = v;
    __syncthreads();
    #pragma unroll
    for (int off = 1; off < 256; off <<= 1) {
        int x = (t >= off) ? s[t - off] : 0;
        __syncthreads();
        s[t] += x;
        __syncthreads();
    }
    boff[t] = s[t] - v;
}

__global__ void k_scanC(int* __restrict__ rowptr, const int* __restrict__ boff)
{
    int i = blockIdx.x * 256 + threadIdx.x;
    rowptr[i] += boff[blockIdx.x];
}

// pass 1: scattered 4B write of edge index only
__global__ void k_scatter_idx(const int* __restrict__ dst, const int* __restrict__ rowptr,
                              int* __restrict__ fill, int* __restrict__ perm_eidx)
{
    int e = blockIdx.x * 256 + threadIdx.x;
    if (e >= N_EDGES) return;
    int d = dst[e];
    int p = rowptr[d] + atomicAdd(&fill[d], 1);
    perm_eidx[p] = e;
}

// pass 2: sequential writes, scattered reads (L2 absorbs)
__global__ void k_gather(const int* __restrict__ perm_eidx, const float* __restrict__ edge_w,
                         const int* __restrict__ src, const int* __restrict__ dst,
                         const float* __restrict__ node_x,
                         int* __restrict__ perm_src, float* __restrict__ perm_sq,
                         f16* __restrict__ perm_ewh)
{
    int pp = blockIdx.x * 256 + threadIdx.x;
    if (pp >= N_EDGES) return;
    int e = perm_eidx[pp];
    int s = src[e], d = dst[e];
    float dx = node_x[s * 3 + 0] - node_x[d * 3 + 0];
    float dy = node_x[s * 3 + 1] - node_x[d * 3 + 1];
    float dz = node_x[s * 3 + 2] - node_x[d * 3 + 2];
    perm_src[pp] = s;
    perm_sq[pp] = dx * dx + dy * dy + dz * dz;
    const float4* pw = (const float4*)(edge_w + (size_t)e * 16);
    float4 w0 = pw[0], w1 = pw[1], w2 = pw[2], w3 = pw[3];
    f16x8 v0, v1;
    v0[0] = (f16)w0.x; v0[1] = (f16)w0.y; v0[2] = (f16)w0.z; v0[3] = (f16)w0.w;
    v0[4] = (f16)w1.x; v0[5] = (f16)w1.y; v0[6] = (f16)w1.z; v0[7] = (f16)w1.w;
    v1[0] = (f16)w2.x; v1[1] = (f16)w2.y; v1[2] = (f16)w2.z; v1[3] = (f16)w2.w;
    v1[4] = (f16)w3.x; v1[5] = (f16)w3.y; v1[6] = (f16)w3.z; v1[7] = (f16)w3.w;
    f16x8* q = (f16x8*)(perm_ewh + (size_t)pp * 16);
    q[0] = v0; q[1] = v1;
}

// ---------------------------------------------------------------------------
// Fused per-layer kernel. Block owns 32 dst nodes + all their edges.
// 512 threads = 8 waves, wave owns 16 output cols. 3 barriers per chunk.
// Hazard notes:
//  - meta double-buffered: chunk c's meta written during chunk c-1's S1;
//    buffer p is re-written at chunk c+1's S1, last read at c's S2 (B2,B3 apart).
//  - dloc for the S4 accumulate is cached into registers at S2 so S4 never
//    reads meta (which chunk c+1's S1 may be overwriting).
//  - h1B written at S3, read at S4; next write is next chunk's S3 (B1,B2 apart).
//  - Atile written at S1, last read at S2 (mm1); next write at next S1 (B2,B3
//    apart). No barrier needed at loop bottom.
// ---------------------------------------------------------------------------
__global__ __launch_bounds__(512, 2) void k_layer(
    const f16* __restrict__ fh_in, f16* __restrict__ fh_out,
    const int* __restrict__ rowptr, const int* __restrict__ perm_src,
    const float* __restrict__ perm_sq, const f16* __restrict__ perm_ewh,
    const float* __restrict__ W_e, const float* __restrict__ b_e,
    const float* __restrict__ W1, const float* __restrict__ b1,
    const float* __restrict__ W2, const float* __restrict__ b2,
    const float* __restrict__ U1, const float* __restrict__ ub1,
    const float* __restrict__ U2, const float* __restrict__ ub2)
{
    const int tid = threadIdx.x;     // 512
    const int wave = tid >> 6;       // 0..7, owns 16 output cols
    const int lane = tid & 63;
    const int l16 = lane & 15;
    const int lq  = lane >> 4;
    const int col = wave * 16 + l16; // 0..127

    // ---- message weight fragments (~68 VGPRs) ----
    f16x8 wef, w1f[12], w2f[4];
    #pragma unroll
    for (int j = 0; j < 8; ++j) {
        int k = lq * 8 + j;
        wef[j] = (k < 16) ? (f16)W_e[(size_t)k * H + col] : (f16)0.0f;
    }
    #pragma unroll
    for (int k = 0; k < 12; ++k)
        #pragma unroll
        for (int j = 0; j < 8; ++j)
            w1f[k][j] = (f16)W1[(size_t)(k * 32 + lq * 8 + j) * H + col];
    #pragma unroll
    for (int k = 0; k < 4; ++k)
        #pragma unroll
        for (int j = 0; j < 8; ++j)
            w2f[k][j] = (f16)W2[(size_t)(k * 32 + lq * 8 + j) * H + col];
    float w1last = W1[(size_t)384 * H + col];
    float b1v = b1[col], b2v = b2[col], bev = b_e[col];

    __shared__ alignas(16) f16 Atile[32][392];   // 25.1 KB
    __shared__ alignas(16) f16 h1B[32][136];     // 8.7 KB
    __shared__ float s_acc[33][132];             // 17.4 KB (row 32 = junk row)
    __shared__ int s_rowptr[33];
    __shared__ int s_srcv[2][32];
    __shared__ int s_dloc[2][32];
    __shared__ float s_sq[2][32];

    const int n0 = blockIdx.x * 32;
    if (tid < 33) s_rowptr[tid] = rowptr[n0 + tid];
    for (int i = tid; i < 33 * 132; i += 512) ((float*)s_acc)[i] = 0.0f;
    __syncthreads();
    const int rs = s_rowptr[0], re = s_rowptr[32];

    // preload meta for chunk 0 into buffer 0
    if (tid < 32) {
        int e = rs + tid;
        int sv = 0; float sqv = 0.0f; int dl = 32;
        if (e < re) {
            sv = perm_src[e]; sqv = perm_sq[e];
            int lo = 0, hi = 32;
            #pragma unroll
            for (int it = 0; it < 5; ++it) {
                int mid = (lo + hi) >> 1;
                if (e >= s_rowptr[mid]) lo = mid; else hi = mid;
            }
            dl = lo;
        }
        s_srcv[0][tid] = sv; s_sq[0][tid] = sqv; s_dloc[0][tid] = dl;
    }
    __syncthreads();

    int p = 0;
    for (int e0 = rs; e0 < re; e0 += 32, p ^= 1) {
        // ---- S1: stage A rows [f_src | f_dst]; we-MFMA -> w cols; prefetch meta ----
        {
            int row = tid >> 4, ch = tid & 15;
            int sv = s_srcv[p][row];
            int dl = s_dloc[p][row]; if (dl > 31) dl = 0;
            int dn = n0 + dl; if (dn >= N_NODES) dn = 0;
            ((int4*)&Atile[row][0])[ch]   = ((const int4*)(fh_in + (size_t)sv * H))[ch];
            ((int4*)&Atile[row][128])[ch] = ((const int4*)(fh_in + (size_t)dn * H))[ch];
        }
        #pragma unroll
        for (int m = 0; m < 2; ++m) {
            f16x8 a;
            int e = e0 + m * 16 + l16;
            if (lq < 2 && e < re) {
                a = *(const f16x8*)(perm_ewh + (size_t)e * 16 + lq * 8);
            } else {
                #pragma unroll
                for (int j = 0; j < 8; ++j) a[j] = (f16)0.0f;
            }
            f32x4 c = {bev, bev, bev, bev};
            c = __builtin_amdgcn_mfma_f32_16x16x32_f16(a, wef, c, 0, 0, 0);
            #pragma unroll
            for (int r = 0; r < 4; ++r)
                Atile[m * 16 + lq * 4 + r][256 + col] = (f16)fmaxf(c[r], 0.0f);
        }
        if (tid < 32) {
            int e = e0 + 32 + tid;
            int sv = 0; float sqv = 0.0f; int dl = 32;
            if (e < re) {
                sv = perm_src[e]; sqv = perm_sq[e];
                int lo = 0, hi = 32;
                #pragma unroll
                for (int it = 0; it < 5; ++it) {
                    int mid = (lo + hi) >> 1;
                    if (e >= s_rowptr[mid]) lo = mid; else hi = mid;
                }
                dl = lo;
            }
            s_srcv[p ^ 1][tid] = sv; s_sq[p ^ 1][tid] = sqv; s_dloc[p ^ 1][tid] = dl;
        }
        __syncthreads();   // B1

        // ---- S2: mm1; cache dloc for S4 ----
        int dlc[8];
        #pragma unroll
        for (int m = 0; m < 2; ++m)
            #pragma unroll
            for (int r = 0; r < 4; ++r)
                dlc[m * 4 + r] = s_dloc[p][m * 16 + lq * 4 + r];
        f32x4 acc1[2];
        #pragma unroll
        for (int m = 0; m < 2; ++m)
            #pragma unroll
            for (int r = 0; r < 4; ++r)
                acc1[m][r] = fmaf(s_sq[p][m * 16 + lq * 4 + r], w1last, b1v);
        #pragma unroll
        for (int k = 0; k < 12; ++k) {
            #pragma unroll
            for (int m = 0; m < 2; ++m) {
                f16x8 a = *(const f16x8*)&Atile[m * 16 + l16][k * 32 + lq * 8];
                acc1[m] = __builtin_amdgcn_mfma_f32_16x16x32_f16(a, w1f[k], acc1[m], 0, 0, 0);
            }
        }
        __syncthreads();   // B2

        // ---- S3: h1 -> h1B ----
        #pragma unroll
        for (int m = 0; m < 2; ++m)
            #pragma unroll
            for (int r = 0; r < 4; ++r)
                h1B[m * 16 + lq * 4 + r][col] = (f16)fmaxf(acc1[m][r], 0.0f);
        __syncthreads();   // B3

        // ---- S4: mm2 + LDS accumulate by dst (no barrier after; see notes) ----
        f32x4 acc2[2];
        #pragma unroll
        for (int m = 0; m < 2; ++m) {
            f32x4 c = {b2v, b2v, b2v, b2v};
            acc2[m] = c;
        }
        #pragma unroll
        for (int k = 0; k < 4; ++k) {
            #pragma unroll
            for (int m = 0; m < 2; ++m) {
                f16x8 a = *(const f16x8*)&h1B[m * 16 + l16][k * 32 + lq * 8];
                acc2[m] = __builtin_amdgcn_mfma_f32_16x16x32_f16(a, w2f[k], acc2[m], 0, 0, 0);
            }
        }
        #pragma unroll
        for (int m = 0; m < 2; ++m)
            #pragma unroll
            for (int r = 0; r < 4; ++r)
                atomicAdd(&s_acc[dlc[m * 4 + r]][col], fmaxf(acc2[m][r], 0.0f));
    }
    __syncthreads();

    // ---- update MLP: f_new = relu(relu((acc+f_old)@U1+ub1)@U2+ub2) ----
    #pragma unroll
    for (int k = 0; k < 4; ++k)
        #pragma unroll
        for (int j = 0; j < 8; ++j) {
            w1f[k][j] = (f16)U1[(size_t)(k * 32 + lq * 8 + j) * H + col];
            w2f[k][j] = (f16)U2[(size_t)(k * 32 + lq * 8 + j) * H + col];
        }
    b1v = ub1[col]; b2v = ub2[col];

    {
        int row = tid >> 4, ch = tid & 15;   // each lane 8 cols
        int n = n0 + row; if (n >= N_NODES) n = 0;
        f16x8 fv = *((const f16x8*)(fh_in + (size_t)n * H) + ch);
        f16x8 t;
        #pragma unroll
        for (int j = 0; j < 8; ++j)
            t[j] = (f16)(s_acc[row][ch * 8 + j] + (float)fv[j]);
        *((f16x8*)&Atile[row][0] + ch) = t;
    }
    __syncthreads();

    f32x4 a1[2];
    #pragma unroll
    for (int m = 0; m < 2; ++m) {
        f32x4 c = {b1v, b1v, b1v, b1v};
        a1[m] = c;
    }
    #pragma unroll
    for (int k = 0; k < 4; ++k) {
        #pragma unroll
        for (int m = 0; m < 2; ++m) {
            f16x8 a = *(const f16x8*)&Atile[m * 16 + l16][k * 32 + lq * 8];
            a1[m] = __builtin_amdgcn_mfma_f32_16x16x32_f16(a, w1f[k], a1[m], 0, 0, 0);
        }
    }
    __syncthreads();
    #pragma unroll
    for (int m = 0; m < 2; ++m)
        #pragma unroll
        for (int r = 0; r < 4; ++r)
            h1B[m * 16 + lq * 4 + r][col] = (f16)fmaxf(a1[m][r], 0.0f);
    __syncthreads();

    f32x4 a2[2];
    #pragma unroll
    for (int m = 0; m < 2; ++m) {
        f32x4 c = {b2v, b2v, b2v, b2v};
        a2[m] = c;
    }
    #pragma unroll
    for (int k = 0; k < 4; ++k) {
        #pragma unroll
        for (int m = 0; m < 2; ++m) {
            f16x8 a = *(const f16x8*)&h1B[m * 16 + l16][k * 32 + lq * 8];
            a2[m] = __builtin_amdgcn_mfma_f32_16x16x32_f16(a, w2f[k], a2[m], 0, 0, 0);
        }
    }
    #pragma unroll
    for (int m = 0; m < 2; ++m)
        #pragma unroll
        for (int r = 0; r < 4; ++r) {
            int row = m * 16 + lq * 4 + r;
            int n = n0 + row;
            if (n < N_NODES)
                fh_out[(size_t)n * H + col] = (f16)fmaxf(a2[m][r], 0.0f);
        }
}

// ---------------------------------------------------------------------------
// Per-graph mean/max readout (graph_ids sorted; f >= 0)
// ---------------------------------------------------------------------------
__global__ void k_readout(const f16* __restrict__ fh, const int* __restrict__ gid,
                          float* __restrict__ gsum, float* __restrict__ gmax,
                          int* __restrict__ gcnt)
{
    __shared__ int s_gid[64];
    const int tid = threadIdx.x;            // 128 threads
    const int base = blockIdx.x * 64;
    if (tid < 64) s_gid[tid] = (base + tid < N_NODES) ? gid[base + tid] : -1;
    __syncthreads();
    if (tid < 64 && base + tid < N_NODES) atomicAdd(&gcnt[s_gid[tid]], 1);

    float lsum = 0.0f, lmax = 0.0f;
    int cur = s_gid[0];
    if (cur >= 0) {
        for (int i = 0; i < 64; ++i) {
            int g = s_gid[i];
            if (g < 0) break;
            if (g != cur) {
                unsafeAtomicAdd(&gsum[(size_t)cur * H + tid], lsum);
                atomicMax((int*)&gmax[(size_t)cur * H + tid], __float_as_int(lmax));
                lsum = 0.0f; lmax = 0.0f; cur = g;
            }
            float v = (float)fh[(size_t)(base + i) * H + tid];
            lsum += v;
            lmax = fmaxf(lmax, v);
        }
        unsafeAtomicAdd(&gsum[(size_t)cur * H + tid], lsum);
        atomicMax((int*)&gmax[(size_t)cur * H + tid], __float_as_int(lmax));
    }
}

__global__ void k_out(const float* __restrict__ gsum, const float* __restrict__ gmax,
                      const int* __restrict__ gcnt, const float* __restrict__ W_out,
                      const float* __restrict__ b_out, float* __restrict__ out)
{
    __shared__ float sm[128], sx[128];
    const int g = blockIdx.x, t = threadIdx.x;
    const float inv = 1.0f / fmaxf((float)gcnt[g], 1.0f);
    sm[t] = gsum[(size_t)g * H + t] * inv;
    sx[t] = gmax[(size_t)g * H + t];
    __syncthreads();
    float acc = b_out[t];
    for (int k = 0; k < H; ++k) {
        acc = fmaf(sm[k], W_out[(size_t)k * 128 + t], acc);
        acc = fmaf(sx[k], W_out[(size_t)(128 + k) * 128 + t], acc);
    }
    out[(size_t)g * 128 + t] = acc;
}

// ---------------------------------------------------------------------------
extern "C" void kernel_launch(void* const* d_in, const int* in_sizes, int n_in,
                              void* d_out, int out_size, void* d_ws, size_t ws_size,
                              hipStream_t stream)
{
    const float* node_f = (const float*)d_in[0];
    const float* node_x = (const float*)d_in[1];
    const float* edge_w = (const float*)d_in[2];
    const int*   src    = (const int*)d_in[3];
    const int*   dst    = (const int*)d_in[4];
    const int*   gid    = (const int*)d_in[5];
    const float* W_in   = (const float*)d_in[6];
    const float* b_in   = (const float*)d_in[7];
    const float* W_e    = (const float*)d_in[8];
    const float* b_e    = (const float*)d_in[9];
    const float* msg_W1 = (const float*)d_in[10];
    const float* msg_b1 = (const float*)d_in[11];
    const float* msg_W2 = (const float*)d_in[12];
    const float* msg_b2 = (const float*)d_in[13];
    const float* upd_W1 = (const float*)d_in[14];
    const float* upd_b1 = (const float*)d_in[15];
    const float* upd_W2 = (const float*)d_in[16];
    const float* upd_b2 = (const float*)d_in[17];
    const float* W_out  = (const float*)d_in[18];
    const float* b_out  = (const float*)d_in[19];
    float* out = (float*)d_out;

    char* ws = (char*)d_ws;
    size_t off = 0;
    f16*   fhA      = (f16*)(ws + off);   off += (size_t)N_NODES * H * 2;      // 12.8 MB
    f16*   fhB      = (f16*)(ws + off);   off += (size_t)N_NODES * H * 2;      // 12.8 MB
    f16*   perm_ewh = (f16*)(ws + off);   off += (size_t)N_EDGES * 16 * 2;     // 19.2 MB
    int*   perm_eidx= (int*)(ws + off);   off += (size_t)N_EDGES * 4;          // 2.4 MB
    int*   perm_src = (int*)(ws + off);   off += (size_t)N_EDGES * 4;          // 2.4 MB
    float* perm_sq  = (float*)(ws + off); off += (size_t)N_EDGES * 4;          // 2.4 MB
    int*   rowptr   = (int*)(ws + off);   off += (size_t)NP * 4;
    int*   cnt      = (int*)(ws + off);   off += (size_t)NP * 4;               // also 'fill'
    int*   bsum     = (int*)(ws + off);   off += 256 * 4;
    int*   boff     = (int*)(ws + off);   off += 256 * 4;
    float* gsum     = (float*)(ws + off); off += (size_t)G_GRAPHS * H * 4;
    float* gmax     = (float*)(ws + off); off += (size_t)G_GRAPHS * H * 4;
    int*   gcnt     = (int*)(ws + off);   off += (size_t)G_GRAPHS * 4;

    k_f0<<<(N_NODES + 7) / 8, 128, 0, stream>>>(node_f, W_in, b_in, fhA);

    (void)hipMemsetAsync(cnt, 0, (size_t)NP * 4, stream);
    k_hist<<<(N_EDGES + 255) / 256, 256, 0, stream>>>(dst, cnt);
    k_scanA<<<NP / 256, 256, 0, stream>>>(cnt, rowptr, bsum);
    k_scanB<<<1, 256, 0, stream>>>(bsum, boff);
    k_scanC<<<NP / 256, 256, 0, stream>>>(rowptr, boff);
    (void)hipMemsetAsync(cnt, 0, (size_t)NP * 4, stream);
    k_scatter_idx<<<(N_EDGES + 255) / 256, 256, 0, stream>>>(dst, rowptr, cnt, perm_eidx);
    k_gather<<<(N_EDGES + 255) / 256, 256, 0, stream>>>(perm_eidx, edge_w, src, dst, node_x,
                                                        perm_src, perm_sq, perm_ewh);

    for (int l = 0; l < 4; ++l) {
        const f16* fin  = (l & 1) ? fhB : fhA;
        f16*       fout = (l & 1) ? fhA : fhB;
        k_layer<<<NTILES, 512, 0, stream>>>(fin, fout, rowptr, perm_src, perm_sq, perm_ewh,
                                            W_e, b_e,
                                            msg_W1 + (size_t)l * 385 * H, msg_b1 + (size_t)l * H,
                                            msg_W2 + (size_t)l * H * H,  msg_b2 + (size_t)l * H,
                                            upd_W1 + (size_t)l * H * H,  upd_b1 + (size_t)l * H,
                                            upd_W2 + (size_t)l * H * H,  upd_b2 + (size_t)l * H);
    }

    (void)hipMemsetAsync(gsum, 0, (size_t)G_GRAPHS * H * 4, stream);
    (void)hipMemsetAsync(gmax, 0, (size_t)G_GRAPHS * H * 4, stream);
    (void)hipMemsetAsync(gcnt, 0, (size_t)G_GRAPHS * 4, stream);
    k_readout<<<(N_NODES + 63) / 64, 128, 0, stream>>>(fhA, gid, gsum, gmax, gcnt);
    k_out<<<G_GRAPHS, 128, 0, stream>>>(gsum, gmax, gcnt, W_out, b_out, out);
}

// Round 6
// 1598.785 us; speedup vs baseline: 1.9809x; 1.9809x over previous
//
#include <hip/hip_runtime.h>

typedef _Float16 f16;
typedef _Float16 f16x8 __attribute__((ext_vector_type(8)));
typedef float f32x4 __attribute__((ext_vector_type(4)));

#define N_NODES 50000
#define N_EDGES 600000
#define G_GRAPHS 128
#define H 128
#define NP 50176              // 196*256, padded node count for scan
#define NT_E 18750            // 600000/32 exact
#define NB_E 1024             // edge-kernel grid
#define NT_N 1563             // ceil(50000/32)

// ---------------------------------------------------------------------------
// f0 = relu(node_f @ W_in + b_in)  -> fh (f16)
// ---------------------------------------------------------------------------
__global__ void k_f0(const float* __restrict__ node_f, const float* __restrict__ W_in,
                     const float* __restrict__ b_in, f16* __restrict__ fh)
{
    __shared__ float sW[32 * 128];
    __shared__ float sx[8][32];
    const int tid = threadIdx.x;     // 128 threads
    const int base = blockIdx.x * 8;
    for (int i = tid; i < 32 * 128; i += 128) sW[i] = W_in[i];
    for (int i = tid; i < 8 * 32; i += 128) {
        int u = i >> 5, k = i & 31;
        int n = base + u;
        sx[u][k] = (n < N_NODES) ? node_f[(size_t)n * 32 + k] : 0.0f;
    }
    __syncthreads();
    const float bj = b_in[tid];
    #pragma unroll
    for (int u = 0; u < 8; ++u) {
        int n = base + u;
        if (n >= N_NODES) break;
        float acc = bj;
        #pragma unroll
        for (int k = 0; k < 32; ++k) acc = fmaf(sx[u][k], sW[k * 128 + tid], acc);
        fh[(size_t)n * H + tid] = (f16)fmaxf(acc, 0.0f);
    }
}

// ---------------------------------------------------------------------------
// CSR build: histogram, scan, idx scatter, sequential gather (dst-sorted perm)
// ---------------------------------------------------------------------------
__global__ void k_hist(const int* __restrict__ dst, int* __restrict__ cnt)
{
    int e = blockIdx.x * 256 + threadIdx.x;
    if (e < N_EDGES) atomicAdd(&cnt[dst[e]], 1);
}

__global__ void k_scanA(const int* __restrict__ cnt, int* __restrict__ rowptr,
                        int* __restrict__ bsum)
{
    __shared__ int s[256];
    const int t = threadIdx.x;
    const int i = blockIdx.x * 256 + t;
    int v = cnt[i];
    s[t] = v;
    __syncthreads();
    #pragma unroll
    for (int off = 1; off < 256; off <<= 1) {
        int x = (t >= off) ? s[t - off] : 0;
        __syncthreads();
        s[t] += x;
        __syncthreads();
    }
    rowptr[i] = s[t] - v;
    if (t == 255) bsum[blockIdx.x] = s[255];
}

__global__ void k_scanB(const int* __restrict__ bsum, int* __restrict__ boff)
{
    __shared__ int s[256];
    const int t = threadIdx.x;
    int v = (t < 196) ? bsum[t] : 0;
    s[t] = v;
    __syncthreads();
    #pragma unroll
    for (int off = 1; off < 256; off <<= 1) {
        int x = (t >= off) ? s[t - off] : 0;
        __syncthreads();
        s[t] += x;
        __syncthreads();
    }
    boff[t] = s[t] - v;
}

__global__ void k_scanC(int* __restrict__ rowptr, const int* __restrict__ boff)
{
    int i = blockIdx.x * 256 + threadIdx.x;
    rowptr[i] += boff[blockIdx.x];
}

__global__ void k_scatter_idx(const int* __restrict__ dst, const int* __restrict__ rowptr,
                              int* __restrict__ fill, int* __restrict__ perm_eidx)
{
    int e = blockIdx.x * 256 + threadIdx.x;
    if (e >= N_EDGES) return;
    int d = dst[e];
    int p = rowptr[d] + atomicAdd(&fill[d], 1);
    perm_eidx[p] = e;
}

__global__ void k_gather(const int* __restrict__ perm_eidx, const float* __restrict__ edge_w,
                         const int* __restrict__ src, const int* __restrict__ dst,
                         const float* __restrict__ node_x,
                         int* __restrict__ perm_src, int* __restrict__ perm_dst,
                         float* __restrict__ perm_sq, f16* __restrict__ perm_ewh)
{
    int pp = blockIdx.x * 256 + threadIdx.x;
    if (pp >= N_EDGES) return;
    int e = perm_eidx[pp];
    int s = src[e], d = dst[e];
    float dx = node_x[s * 3 + 0] - node_x[d * 3 + 0];
    float dy = node_x[s * 3 + 1] - node_x[d * 3 + 1];
    float dz = node_x[s * 3 + 2] - node_x[d * 3 + 2];
    perm_src[pp] = s;
    perm_dst[pp] = d;
    perm_sq[pp] = dx * dx + dy * dy + dz * dz;
    const float4* pw = (const float4*)(edge_w + (size_t)e * 16);
    float4 w0 = pw[0], w1 = pw[1], w2 = pw[2], w3 = pw[3];
    f16x8 v0, v1;
    v0[0] = (f16)w0.x; v0[1] = (f16)w0.y; v0[2] = (f16)w0.z; v0[3] = (f16)w0.w;
    v0[4] = (f16)w1.x; v0[5] = (f16)w1.y; v0[6] = (f16)w1.z; v0[7] = (f16)w1.w;
    v1[0] = (f16)w2.x; v1[1] = (f16)w2.y; v1[2] = (f16)w2.z; v1[3] = (f16)w2.w;
    v1[4] = (f16)w3.x; v1[5] = (f16)w3.y; v1[6] = (f16)w3.z; v1[7] = (f16)w3.w;
    f16x8* q = (f16x8*)(perm_ewh + (size_t)pp * 16);
    q[0] = v0; q[1] = v1;
}

// ---------------------------------------------------------------------------
// Edge-parallel message kernel over dst-sorted 32-edge tiles.
// 512 thr = 8 waves, wave owns 16 cols. Contiguous tile range per block.
// 3 barriers/tile; run-compressed fp32 atomics into msum.
// ---------------------------------------------------------------------------
__global__ __launch_bounds__(512, 4) void k_edge2(
    const f16* __restrict__ fh,
    const int* __restrict__ perm_src, const int* __restrict__ perm_dst,
    const float* __restrict__ perm_sq, const f16* __restrict__ perm_ewh,
    const float* __restrict__ W_e, const float* __restrict__ b_e,
    const float* __restrict__ W1, const float* __restrict__ b1,
    const float* __restrict__ W2, const float* __restrict__ b2,
    float* __restrict__ msum)
{
    const int tid = threadIdx.x;
    const int wave = tid >> 6;
    const int lane = tid & 63;
    const int l16 = lane & 15;
    const int lq  = lane >> 4;
    const int col = wave * 16 + l16;

    // fragments (~115 VGPR incl. accs)
    f16x8 wef, w1f[12], w2f[4];
    #pragma unroll
    for (int j = 0; j < 8; ++j) {
        int k = lq * 8 + j;
        wef[j] = (k < 16) ? (f16)W_e[(size_t)k * H + col] : (f16)0.0f;
    }
    #pragma unroll
    for (int k = 0; k < 12; ++k)
        #pragma unroll
        for (int j = 0; j < 8; ++j)
            w1f[k][j] = (f16)W1[(size_t)(k * 32 + lq * 8 + j) * H + col];
    #pragma unroll
    for (int k = 0; k < 4; ++k)
        #pragma unroll
        for (int j = 0; j < 8; ++j)
            w2f[k][j] = (f16)W2[(size_t)(k * 32 + lq * 8 + j) * H + col];
    const float w1last = W1[(size_t)384 * H + col];
    const float b1v = b1[col], b2v = b2[col], bev = b_e[col];

    __shared__ alignas(16) f16 Atile[32][392];   // 25.1 KB
    __shared__ alignas(16) f16 h1B[32][136];     // 8.7 KB
    __shared__ int   s_src[2][32];
    __shared__ int   s_dst[2][32];
    __shared__ float s_sq[2][32];

    const int b = blockIdx.x;
    const int t0 = (int)((long)b * NT_E / NB_E);
    const int t1 = (int)((long)(b + 1) * NT_E / NB_E);

    if (tid < 32) {                       // prefetch meta for t0
        int e = t0 * 32 + tid;
        s_src[0][tid] = perm_src[e];
        s_dst[0][tid] = perm_dst[e];
        s_sq[0][tid]  = perm_sq[e];
    }
    __syncthreads();

    int p = 0;
    for (int t = t0; t < t1; ++t, p ^= 1) {
        // ---- S1: stage [f_src|f_dst]; we-MFMA -> w cols; prefetch next meta ----
        {
            int row = tid >> 4, ch = tid & 15;
            int sv = s_src[p][row];
            int dv = s_dst[p][row];
            ((int4*)&Atile[row][0])[ch]   = ((const int4*)(fh + (size_t)sv * H))[ch];
            ((int4*)&Atile[row][128])[ch] = ((const int4*)(fh + (size_t)dv * H))[ch];
        }
        #pragma unroll
        for (int m = 0; m < 2; ++m) {
            f16x8 a;
            if (lq < 2) {
                int e = t * 32 + m * 16 + l16;
                a = *(const f16x8*)(perm_ewh + (size_t)e * 16 + lq * 8);
            } else {
                #pragma unroll
                for (int j = 0; j < 8; ++j) a[j] = (f16)0.0f;
            }
            f32x4 c = {bev, bev, bev, bev};
            c = __builtin_amdgcn_mfma_f32_16x16x32_f16(a, wef, c, 0, 0, 0);
            #pragma unroll
            for (int r = 0; r < 4; ++r)
                Atile[m * 16 + lq * 4 + r][256 + col] = (f16)fmaxf(c[r], 0.0f);
        }
        if (tid < 32 && t + 1 < t1) {
            int e = (t + 1) * 32 + tid;
            s_src[p ^ 1][tid] = perm_src[e];
            s_dst[p ^ 1][tid] = perm_dst[e];
            s_sq[p ^ 1][tid]  = perm_sq[e];
        }
        __syncthreads();   // B1

        // ---- S2: cache dst ids; mm1 ----
        int dc[8];
        #pragma unroll
        for (int m = 0; m < 2; ++m)
            #pragma unroll
            for (int r = 0; r < 4; ++r)
                dc[m * 4 + r] = s_dst[p][m * 16 + lq * 4 + r];
        f32x4 acc1[2];
        #pragma unroll
        for (int m = 0; m < 2; ++m)
            #pragma unroll
            for (int r = 0; r < 4; ++r)
                acc1[m][r] = fmaf(s_sq[p][m * 16 + lq * 4 + r], w1last, b1v);
        #pragma unroll
        for (int k = 0; k < 12; ++k) {
            #pragma unroll
            for (int m = 0; m < 2; ++m) {
                f16x8 a = *(const f16x8*)&Atile[m * 16 + l16][k * 32 + lq * 8];
                acc1[m] = __builtin_amdgcn_mfma_f32_16x16x32_f16(a, w1f[k], acc1[m], 0, 0, 0);
            }
        }
        __syncthreads();   // B2

        // ---- S3: h1 -> h1B ----
        #pragma unroll
        for (int m = 0; m < 2; ++m)
            #pragma unroll
            for (int r = 0; r < 4; ++r)
                h1B[m * 16 + lq * 4 + r][col] = (f16)fmaxf(acc1[m][r], 0.0f);
        __syncthreads();   // B3

        // ---- S4: mm2; run-compressed atomic scatter (no trailing barrier) ----
        f32x4 acc2[2];
        #pragma unroll
        for (int m = 0; m < 2; ++m) {
            f32x4 c = {b2v, b2v, b2v, b2v};
            acc2[m] = c;
        }
        #pragma unroll
        for (int k = 0; k < 4; ++k) {
            #pragma unroll
            for (int m = 0; m < 2; ++m) {
                f16x8 a = *(const f16x8*)&h1B[m * 16 + l16][k * 32 + lq * 8];
                acc2[m] = __builtin_amdgcn_mfma_f32_16x16x32_f16(a, w2f[k], acc2[m], 0, 0, 0);
            }
        }
        #pragma unroll
        for (int m = 0; m < 2; ++m) {
            float run = fmaxf(acc2[m][0], 0.0f);
            int cd = dc[m * 4];
            #pragma unroll
            for (int r = 1; r < 4; ++r) {
                float v = fmaxf(acc2[m][r], 0.0f);
                int d = dc[m * 4 + r];
                if (d == cd) {
                    run += v;
                } else {
                    unsafeAtomicAdd(&msum[(size_t)cd * H + col], run);
                    run = v; cd = d;
                }
            }
            unsafeAtomicAdd(&msum[(size_t)cd * H + col], run);
        }
    }
}

// ---------------------------------------------------------------------------
// Node update: fh = relu(relu((msum+fh)@U1+b1)@U2+b2)   (in-place on fh)
// ---------------------------------------------------------------------------
__global__ __launch_bounds__(256, 4) void k_update(
    const float* __restrict__ msum, f16* __restrict__ fh,
    const float* __restrict__ W1, const float* __restrict__ b1,
    const float* __restrict__ W2, const float* __restrict__ b2)
{
    const int tid = threadIdx.x;
    const int wave = tid >> 6;       // 0..3
    const int lane = tid & 63;
    const int l16 = lane & 15;
    const int lq = lane >> 4;
    const int colbase = wave * 32;

    f16x8 w1fr[4][2], w2fr[4][2];
    float b1v[2], b2v[2];
    #pragma unroll
    for (int nt = 0; nt < 2; ++nt) {
        const int col = colbase + nt * 16 + l16;
        #pragma unroll
        for (int k = 0; k < 4; ++k) {
            f16x8 v1, v2;
            #pragma unroll
            for (int j = 0; j < 8; ++j) {
                v1[j] = (f16)W1[(size_t)(k * 32 + lq * 8 + j) * H + col];
                v2[j] = (f16)W2[(size_t)(k * 32 + lq * 8 + j) * H + col];
            }
            w1fr[k][nt] = v1;
            w2fr[k][nt] = v2;
        }
        b1v[nt] = b1[col];
        b2v[nt] = b2[col];
    }

    __shared__ alignas(16) f16 U[32][136];
    for (int tile = blockIdx.x; tile < NT_N; tile += gridDim.x) {
        __syncthreads();
        const int n0 = tile * 32;
        {
            int row = tid >> 3, ch = tid & 7;   // 16 cols per thread
            int n = n0 + row;
            if (n < N_NODES) {
                const float4* pm = (const float4*)(msum + (size_t)n * H) + ch * 4;
                const f16x8*  pf = (const f16x8*)(fh + (size_t)n * H) + ch * 2;
                f16x8 f0 = pf[0], f1 = pf[1];
                float4 a0 = pm[0], a1 = pm[1], a2 = pm[2], a3 = pm[3];
                f16 tmp[16];
                tmp[0]  = (f16)(a0.x + (float)f0[0]); tmp[1]  = (f16)(a0.y + (float)f0[1]);
                tmp[2]  = (f16)(a0.z + (float)f0[2]); tmp[3]  = (f16)(a0.w + (float)f0[3]);
                tmp[4]  = (f16)(a1.x + (float)f0[4]); tmp[5]  = (f16)(a1.y + (float)f0[5]);
                tmp[6]  = (f16)(a1.z + (float)f0[6]); tmp[7]  = (f16)(a1.w + (float)f0[7]);
                tmp[8]  = (f16)(a2.x + (float)f1[0]); tmp[9]  = (f16)(a2.y + (float)f1[1]);
                tmp[10] = (f16)(a2.z + (float)f1[2]); tmp[11] = (f16)(a2.w + (float)f1[3]);
                tmp[12] = (f16)(a3.x + (float)f1[4]); tmp[13] = (f16)(a3.y + (float)f1[5]);
                tmp[14] = (f16)(a3.z + (float)f1[6]); tmp[15] = (f16)(a3.w + (float)f1[7]);
                int4* q0 = (int4*)(&U[row][ch * 16]);
                q0[0] = ((const int4*)tmp)[0];
                q0[1] = ((const int4*)tmp)[1];
            }
        }
        __syncthreads();

        f32x4 acc[2][2];
        #pragma unroll
        for (int m = 0; m < 2; ++m)
            #pragma unroll
            for (int nt = 0; nt < 2; ++nt) {
                f32x4 c = {b1v[nt], b1v[nt], b1v[nt], b1v[nt]};
                acc[m][nt] = c;
            }
        #pragma unroll
        for (int k = 0; k < 4; ++k) {
            #pragma unroll
            for (int m = 0; m < 2; ++m) {
                f16x8 a = *(const f16x8*)&U[m * 16 + l16][k * 32 + lq * 8];
                #pragma unroll
                for (int nt = 0; nt < 2; ++nt)
                    acc[m][nt] = __builtin_amdgcn_mfma_f32_16x16x32_f16(a, w1fr[k][nt], acc[m][nt], 0, 0, 0);
            }
        }
        __syncthreads();
        #pragma unroll
        for (int m = 0; m < 2; ++m)
            #pragma unroll
            for (int nt = 0; nt < 2; ++nt)
                #pragma unroll
                for (int r = 0; r < 4; ++r)
                    U[m * 16 + lq * 4 + r][colbase + nt * 16 + l16] = (f16)fmaxf(acc[m][nt][r], 0.0f);
        __syncthreads();

        f32x4 acc2[2][2];
        #pragma unroll
        for (int m = 0; m < 2; ++m)
            #pragma unroll
            for (int nt = 0; nt < 2; ++nt) {
                f32x4 c = {b2v[nt], b2v[nt], b2v[nt], b2v[nt]};
                acc2[m][nt] = c;
            }
        #pragma unroll
        for (int k = 0; k < 4; ++k) {
            #pragma unroll
            for (int m = 0; m < 2; ++m) {
                f16x8 a = *(const f16x8*)&U[m * 16 + l16][k * 32 + lq * 8];
                #pragma unroll
                for (int nt = 0; nt < 2; ++nt)
                    acc2[m][nt] = __builtin_amdgcn_mfma_f32_16x16x32_f16(a, w2fr[k][nt], acc2[m][nt], 0, 0, 0);
            }
        }
        #pragma unroll
        for (int m = 0; m < 2; ++m)
            #pragma unroll
            for (int nt = 0; nt < 2; ++nt)
                #pragma unroll
                for (int r = 0; r < 4; ++r) {
                    int row = m * 16 + lq * 4 + r;
                    int n = n0 + row;
                    if (n < N_NODES)
                        fh[(size_t)n * H + colbase + nt * 16 + l16] = (f16)fmaxf(acc2[m][nt][r], 0.0f);
                }
    }
}

// ---------------------------------------------------------------------------
// Per-graph mean/max readout (graph_ids sorted; f >= 0)
// ---------------------------------------------------------------------------
__global__ void k_readout(const f16* __restrict__ fh, const int* __restrict__ gid,
                          float* __restrict__ gsum, float* __restrict__ gmax,
                          int* __restrict__ gcnt)
{
    __shared__ int s_gid[64];
    const int tid = threadIdx.x;            // 128 threads
    const int base = blockIdx.x * 64;
    if (tid < 64) s_gid[tid] = (base + tid < N_NODES) ? gid[base + tid] : -1;
    __syncthreads();
    if (tid < 64 && base + tid < N_NODES) atomicAdd(&gcnt[s_gid[tid]], 1);

    float lsum = 0.0f, lmax = 0.0f;
    int cur = s_gid[0];
    if (cur >= 0) {
        for (int i = 0; i < 64; ++i) {
            int g = s_gid[i];
            if (g < 0) break;
            if (g != cur) {
                unsafeAtomicAdd(&gsum[(size_t)cur * H + tid], lsum);
                atomicMax((int*)&gmax[(size_t)cur * H + tid], __float_as_int(lmax));
                lsum = 0.0f; lmax = 0.0f; cur = g;
            }
            float v = (float)fh[(size_t)(base + i) * H + tid];
            lsum += v;
            lmax = fmaxf(lmax, v);
        }
        unsafeAtomicAdd(&gsum[(size_t)cur * H + tid], lsum);
        atomicMax((int*)&gmax[(size_t)cur * H + tid], __float_as_int(lmax));
    }
}

__global__ void k_out(const float* __restrict__ gsum, const float* __restrict__ gmax,
                      const int* __restrict__ gcnt, const float* __restrict__ W_out,
                      const float* __restrict__ b_out, float* __restrict__ out)
{
    __shared__ float sm[128], sx[128];
    const int g = blockIdx.x, t = threadIdx.x;
    const float inv = 1.0f / fmaxf((float)gcnt[g], 1.0f);
    sm[t] = gsum[(size_t)g * H + t] * inv;
    sx[t] = gmax[(size_t)g * H + t];
    __syncthreads();
    float acc = b_out[t];
    for (int k = 0; k < H; ++k) {
        acc = fmaf(sm[k], W_out[(size_t)k * 128 + t], acc);
        acc = fmaf(sx[k], W_out[(size_t)(128 + k) * 128 + t], acc);
    }
    out[(size_t)g * 128 + t] = acc;
}

// ---------------------------------------------------------------------------
extern "C" void kernel_launch(void* const* d_in, const int* in_sizes, int n_in,
                              void* d_out, int out_size, void* d_ws, size_t ws_size,
                              hipStream_t stream)
{
    const float* node_f = (const float*)d_in[0];
    const float* node_x = (const float*)d_in[1];
    const float* edge_w = (const float*)d_in[2];
    const int*   src    = (const int*)d_in[3];
    const int*   dst    = (const int*)d_in[4];
    const int*   gid    = (const int*)d_in[5];
    const float* W_in   = (const float*)d_in[6];
    const float* b_in   = (const float*)d_in[7];
    const float* W_e    = (const float*)d_in[8];
    const float* b_e    = (const float*)d_in[9];
    const float* msg_W1 = (const float*)d_in[10];
    const float* msg_b1 = (const float*)d_in[11];
    const float* msg_W2 = (const float*)d_in[12];
    const float* msg_b2 = (const float*)d_in[13];
    const float* upd_W1 = (const float*)d_in[14];
    const float* upd_b1 = (const float*)d_in[15];
    const float* upd_W2 = (const float*)d_in[16];
    const float* upd_b2 = (const float*)d_in[17];
    const float* W_out  = (const float*)d_in[18];
    const float* b_out  = (const float*)d_in[19];
    float* out = (float*)d_out;

    char* ws = (char*)d_ws;
    size_t off = 0;
    f16*   fh       = (f16*)(ws + off);   off += (size_t)N_NODES * H * 2;      // 12.8 MB
    f16*   perm_ewh = (f16*)(ws + off);   off += (size_t)N_EDGES * 16 * 2;     // 19.2 MB
    int*   perm_src = (int*)(ws + off);   off += (size_t)N_EDGES * 4;          // 2.4 MB
    int*   perm_dst = (int*)(ws + off);   off += (size_t)N_EDGES * 4;          // 2.4 MB
    float* perm_sq  = (float*)(ws + off); off += (size_t)N_EDGES * 4;          // 2.4 MB
    int*   rowptr   = (int*)(ws + off);   off += (size_t)NP * 4;
    int*   cnt      = (int*)(ws + off);   off += (size_t)NP * 4;               // also 'fill'
    int*   bsum     = (int*)(ws + off);   off += 256 * 4;
    int*   boff     = (int*)(ws + off);   off += 256 * 4;
    float* msum     = (float*)(ws + off); off += (size_t)N_NODES * H * 4;      // 25.6 MB
    float* gsum     = (float*)(ws + off); off += (size_t)G_GRAPHS * H * 4;
    float* gmax     = (float*)(ws + off); off += (size_t)G_GRAPHS * H * 4;
    int*   gcnt     = (int*)(ws + off);   off += (size_t)G_GRAPHS * 4;
    int*   perm_eidx = (int*)msum;        // aliased: eidx only used pre-layers

    k_f0<<<(N_NODES + 7) / 8, 128, 0, stream>>>(node_f, W_in, b_in, fh);

    (void)hipMemsetAsync(cnt, 0, (size_t)NP * 4, stream);
    k_hist<<<(N_EDGES + 255) / 256, 256, 0, stream>>>(dst, cnt);
    k_scanA<<<NP / 256, 256, 0, stream>>>(cnt, rowptr, bsum);
    k_scanB<<<1, 256, 0, stream>>>(bsum, boff);
    k_scanC<<<NP / 256, 256, 0, stream>>>(rowptr, boff);
    (void)hipMemsetAsync(cnt, 0, (size_t)NP * 4, stream);
    k_scatter_idx<<<(N_EDGES + 255) / 256, 256, 0, stream>>>(dst, rowptr, cnt, perm_eidx);
    k_gather<<<(N_EDGES + 255) / 256, 256, 0, stream>>>(perm_eidx, edge_w, src, dst, node_x,
                                                        perm_src, perm_dst, perm_sq, perm_ewh);

    for (int l = 0; l < 4; ++l) {
        (void)hipMemsetAsync(msum, 0, (size_t)N_NODES * H * 4, stream);
        k_edge2<<<NB_E, 512, 0, stream>>>(fh, perm_src, perm_dst, perm_sq, perm_ewh,
                                          W_e, b_e,
                                          msg_W1 + (size_t)l * 385 * H, msg_b1 + (size_t)l * H,
                                          msg_W2 + (size_t)l * H * H,  msg_b2 + (size_t)l * H,
                                          msum);
        k_update<<<512, 256, 0, stream>>>(msum, fh,
                                          upd_W1 + (size_t)l * H * H, upd_b1 + (size_t)l * H,
                                          upd_W2 + (size_t)l * H * H, upd_b2 + (size_t)l * H);
    }

    (void)hipMemsetAsync(gsum, 0, (size_t)G_GRAPHS * H * 4, stream);
    (void)hipMemsetAsync(gmax, 0, (size_t)G_GRAPHS * H * 4, stream);
    (void)hipMemsetAsync(gcnt, 0, (size_t)G_GRAPHS * 4, stream);
    k_readout<<<(N_NODES + 63) / 64, 128, 0, stream>>>(fh, gid, gsum, gmax, gcnt);
    k_out<<<G_GRAPHS, 128, 0, stream>>>(gsum, gmax, gcnt, W_out, b_out, out);
}

// Round 7
// 1488.747 us; speedup vs baseline: 2.1273x; 1.0739x over previous
//
#include <hip/hip_runtime.h>

typedef _Float16 f16;
typedef _Float16 f16x8 __attribute__((ext_vector_type(8)));
typedef float f32x4 __attribute__((ext_vector_type(4)));

#define N_NODES 50000
#define N_EDGES 600000
#define G_GRAPHS 128
#define H 128
#define NP 50176              // 196*256, padded node count for scan
#define NT_E 18750            // 600000/32 exact
#define NB_E 1024             // edge-kernel grid (8*128 for XCD remap)
#define NT_N 1563             // ceil(50000/32)

// ---------------------------------------------------------------------------
// f0 = relu(node_f @ W_in + b_in)  -> fh (f16)
// ---------------------------------------------------------------------------
__global__ void k_f0(const float* __restrict__ node_f, const float* __restrict__ W_in,
                     const float* __restrict__ b_in, f16* __restrict__ fh)
{
    __shared__ float sW[32 * 128];
    __shared__ float sx[8][32];
    const int tid = threadIdx.x;     // 128 threads
    const int base = blockIdx.x * 8;
    for (int i = tid; i < 32 * 128; i += 128) sW[i] = W_in[i];
    for (int i = tid; i < 8 * 32; i += 128) {
        int u = i >> 5, k = i & 31;
        int n = base + u;
        sx[u][k] = (n < N_NODES) ? node_f[(size_t)n * 32 + k] : 0.0f;
    }
    __syncthreads();
    const float bj = b_in[tid];
    #pragma unroll
    for (int u = 0; u < 8; ++u) {
        int n = base + u;
        if (n >= N_NODES) break;
        float acc = bj;
        #pragma unroll
        for (int k = 0; k < 32; ++k) acc = fmaf(sx[u][k], sW[k * 128 + tid], acc);
        fh[(size_t)n * H + tid] = (f16)fmaxf(acc, 0.0f);
    }
}

// ---------------------------------------------------------------------------
// CSR build: histogram, scan, idx scatter, sequential gather (dst-sorted perm)
// ---------------------------------------------------------------------------
__global__ void k_hist(const int* __restrict__ dst, int* __restrict__ cnt)
{
    int e = blockIdx.x * 256 + threadIdx.x;
    if (e < N_EDGES) atomicAdd(&cnt[dst[e]], 1);
}

__global__ void k_scanA(const int* __restrict__ cnt, int* __restrict__ rowptr,
                        int* __restrict__ bsum)
{
    __shared__ int s[256];
    const int t = threadIdx.x;
    const int i = blockIdx.x * 256 + t;
    int v = cnt[i];
    s[t] = v;
    __syncthreads();
    #pragma unroll
    for (int off = 1; off < 256; off <<= 1) {
        int x = (t >= off) ? s[t - off] : 0;
        __syncthreads();
        s[t] += x;
        __syncthreads();
    }
    rowptr[i] = s[t] - v;
    if (t == 255) bsum[blockIdx.x] = s[255];
}

__global__ void k_scanB(const int* __restrict__ bsum, int* __restrict__ boff)
{
    __shared__ int s[256];
    const int t = threadIdx.x;
    int v = (t < 196) ? bsum[t] : 0;
    s[t] = v;
    __syncthreads();
    #pragma unroll
    for (int off = 1; off < 256; off <<= 1) {
        int x = (t >= off) ? s[t - off] : 0;
        __syncthreads();
        s[t] += x;
        __syncthreads();
    }
    boff[t] = s[t] - v;
}

__global__ void k_scanC(int* __restrict__ rowptr, const int* __restrict__ boff)
{
    int i = blockIdx.x * 256 + threadIdx.x;
    rowptr[i] += boff[blockIdx.x];
}

__global__ void k_scatter_idx(const int* __restrict__ dst, const int* __restrict__ rowptr,
                              int* __restrict__ fill, int* __restrict__ perm_eidx)
{
    int e = blockIdx.x * 256 + threadIdx.x;
    if (e >= N_EDGES) return;
    int d = dst[e];
    int p = rowptr[d] + atomicAdd(&fill[d], 1);
    perm_eidx[p] = e;
}

__global__ void k_gather(const int* __restrict__ perm_eidx, const float* __restrict__ edge_w,
                         const int* __restrict__ src, const int* __restrict__ dst,
                         const float* __restrict__ node_x,
                         int* __restrict__ perm_src, int* __restrict__ perm_dst,
                         float* __restrict__ perm_sq, f16* __restrict__ perm_ewh)
{
    int pp = blockIdx.x * 256 + threadIdx.x;
    if (pp >= N_EDGES) return;
    int e = perm_eidx[pp];
    int s = src[e], d = dst[e];
    float dx = node_x[s * 3 + 0] - node_x[d * 3 + 0];
    float dy = node_x[s * 3 + 1] - node_x[d * 3 + 1];
    float dz = node_x[s * 3 + 2] - node_x[d * 3 + 2];
    perm_src[pp] = s;
    perm_dst[pp] = d;
    perm_sq[pp] = dx * dx + dy * dy + dz * dz;
    const float4* pw = (const float4*)(edge_w + (size_t)e * 16);
    float4 w0 = pw[0], w1 = pw[1], w2 = pw[2], w3 = pw[3];
    f16x8 v0, v1;
    v0[0] = (f16)w0.x; v0[1] = (f16)w0.y; v0[2] = (f16)w0.z; v0[3] = (f16)w0.w;
    v0[4] = (f16)w1.x; v0[5] = (f16)w1.y; v0[6] = (f16)w1.z; v0[7] = (f16)w1.w;
    v1[0] = (f16)w2.x; v1[1] = (f16)w2.y; v1[2] = (f16)w2.z; v1[3] = (f16)w2.w;
    v1[4] = (f16)w3.x; v1[5] = (f16)w3.y; v1[6] = (f16)w3.z; v1[7] = (f16)w3.w;
    f16x8* q = (f16x8*)(perm_ewh + (size_t)pp * 16);
    q[0] = v0; q[1] = v1;
}

// ---------------------------------------------------------------------------
// Edge-parallel message kernel over dst-sorted 32-edge tiles.
// 512 thr = 8 waves, wave owns 16 cols. XCD-contiguous tile ranges.
// Within-tile edge permutation: tile row (m*16+lq*4+r) <-> edge j=lq*8+m*4+r,
// so each thread's 8 accumulator rows are 8 CONSECUTIVE sorted edges ->
// maximal run compression before the fp32 atomic scatter.
// ---------------------------------------------------------------------------
__global__ __launch_bounds__(512, 2) void k_edge2(
    const f16* __restrict__ fh,
    const int* __restrict__ perm_src, const int* __restrict__ perm_dst,
    const float* __restrict__ perm_sq, const f16* __restrict__ perm_ewh,
    const float* __restrict__ W_e, const float* __restrict__ b_e,
    const float* __restrict__ W1, const float* __restrict__ b1,
    const float* __restrict__ W2, const float* __restrict__ b2,
    float* __restrict__ msum)
{
    const int tid = threadIdx.x;
    const int wave = tid >> 6;
    const int lane = tid & 63;
    const int l16 = lane & 15;
    const int lq  = lane >> 4;
    const int col = wave * 16 + l16;

    // fragments (~115 VGPR incl. accs) -- (512,2) caps at 256, no spill
    f16x8 wef, w1f[12], w2f[4];
    #pragma unroll
    for (int j = 0; j < 8; ++j) {
        int k = lq * 8 + j;
        wef[j] = (k < 16) ? (f16)W_e[(size_t)k * H + col] : (f16)0.0f;
    }
    #pragma unroll
    for (int k = 0; k < 12; ++k)
        #pragma unroll
        for (int j = 0; j < 8; ++j)
            w1f[k][j] = (f16)W1[(size_t)(k * 32 + lq * 8 + j) * H + col];
    #pragma unroll
    for (int k = 0; k < 4; ++k)
        #pragma unroll
        for (int j = 0; j < 8; ++j)
            w2f[k][j] = (f16)W2[(size_t)(k * 32 + lq * 8 + j) * H + col];
    const float w1last = W1[(size_t)384 * H + col];
    const float b1v = b1[col], b2v = b2[col], bev = b_e[col];

    __shared__ alignas(16) f16 Atile[32][392];   // 25.1 KB
    __shared__ alignas(16) f16 h1B[32][136];     // 8.7 KB
    __shared__ int   s_src[2][32];
    __shared__ int   s_dst[2][32];
    __shared__ float s_sq[2][32];

    // XCD-contiguous remap: XCD x (= blockIdx%8) gets ranges [x*128,(x+1)*128)
    const int b = ((blockIdx.x & 7) << 7) | (blockIdx.x >> 3);
    const int t0 = (int)((long)b * NT_E / NB_E);
    const int t1 = (int)((long)(b + 1) * NT_E / NB_E);

    if (tid < 32) {                       // prefetch meta for t0 (edge order)
        int e = t0 * 32 + tid;
        s_src[0][tid] = perm_src[e];
        s_dst[0][tid] = perm_dst[e];
        s_sq[0][tid]  = perm_sq[e];
    }
    __syncthreads();

    int p = 0;
    for (int t = t0; t < t1; ++t, p ^= 1) {
        // ---- S1: stage [f_src|f_dst] (rows permuted); we-MFMA; prefetch meta ----
        {
            int row = tid >> 4, ch = tid & 15;
            int j = ((row >> 2) & 3) * 8 + (row >> 4) * 4 + (row & 3); // eperm(row)
            int sv = s_src[p][j];
            int dv = s_dst[p][j];
            ((int4*)&Atile[row][0])[ch]   = ((const int4*)(fh + (size_t)sv * H))[ch];
            ((int4*)&Atile[row][128])[ch] = ((const int4*)(fh + (size_t)dv * H))[ch];
        }
        #pragma unroll
        for (int m = 0; m < 2; ++m) {
            f16x8 a;
            if (lq < 2) {
                // A lane l16 holds tile row m*16+l16 -> edge j=eperm(row)
                int j = (l16 >> 2) * 8 + m * 4 + (l16 & 3);
                int e = t * 32 + j;
                a = *(const f16x8*)(perm_ewh + (size_t)e * 16 + lq * 8);
            } else {
                #pragma unroll
                for (int jj = 0; jj < 8; ++jj) a[jj] = (f16)0.0f;
            }
            f32x4 c = {bev, bev, bev, bev};
            c = __builtin_amdgcn_mfma_f32_16x16x32_f16(a, wef, c, 0, 0, 0);
            #pragma unroll
            for (int r = 0; r < 4; ++r)
                Atile[m * 16 + lq * 4 + r][256 + col] = (f16)fmaxf(c[r], 0.0f);
        }
        if (tid < 32 && t + 1 < t1) {
            int e = (t + 1) * 32 + tid;
            s_src[p ^ 1][tid] = perm_src[e];
            s_dst[p ^ 1][tid] = perm_dst[e];
            s_sq[p ^ 1][tid]  = perm_sq[e];
        }
        __syncthreads();   // B1

        // ---- S2: cache dst ids (j-order: 8 consecutive edges); mm1 ----
        int dc[8];
        f32x4 acc1[2];
        #pragma unroll
        for (int m = 0; m < 2; ++m)
            #pragma unroll
            for (int r = 0; r < 4; ++r) {
                int j = lq * 8 + m * 4 + r;      // edge for tile row m*16+lq*4+r
                dc[m * 4 + r] = s_dst[p][j];
                acc1[m][r] = fmaf(s_sq[p][j], w1last, b1v);
            }
        #pragma unroll
        for (int k = 0; k < 12; ++k) {
            #pragma unroll
            for (int m = 0; m < 2; ++m) {
                f16x8 a = *(const f16x8*)&Atile[m * 16 + l16][k * 32 + lq * 8];
                acc1[m] = __builtin_amdgcn_mfma_f32_16x16x32_f16(a, w1f[k], acc1[m], 0, 0, 0);
            }
        }
        __syncthreads();   // B2

        // ---- S3: h1 -> h1B ----
        #pragma unroll
        for (int m = 0; m < 2; ++m)
            #pragma unroll
            for (int r = 0; r < 4; ++r)
                h1B[m * 16 + lq * 4 + r][col] = (f16)fmaxf(acc1[m][r], 0.0f);
        __syncthreads();   // B3

        // ---- S4: mm2; run-compressed atomic scatter over 8 consecutive edges ----
        f32x4 acc2[2];
        #pragma unroll
        for (int m = 0; m < 2; ++m) {
            f32x4 c = {b2v, b2v, b2v, b2v};
            acc2[m] = c;
        }
        #pragma unroll
        for (int k = 0; k < 4; ++k) {
            #pragma unroll
            for (int m = 0; m < 2; ++m) {
                f16x8 a = *(const f16x8*)&h1B[m * 16 + l16][k * 32 + lq * 8];
                acc2[m] = __builtin_amdgcn_mfma_f32_16x16x32_f16(a, w2f[k], acc2[m], 0, 0, 0);
            }
        }
        {
            float run = fmaxf(acc2[0][0], 0.0f);
            int cd = dc[0];
            #pragma unroll
            for (int i = 1; i < 8; ++i) {
                float v = fmaxf(acc2[i >> 2][i & 3], 0.0f);
                int d = dc[i];
                if (d == cd) {
                    run += v;
                } else {
                    unsafeAtomicAdd(&msum[(size_t)cd * H + col], run);
                    run = v; cd = d;
                }
            }
            unsafeAtomicAdd(&msum[(size_t)cd * H + col], run);
        }
    }
}

// ---------------------------------------------------------------------------
// Node update: fh = relu(relu((msum+fh)@U1+b1)@U2+b2)   (in-place on fh)
// ---------------------------------------------------------------------------
__global__ __launch_bounds__(256, 4) void k_update(
    const float* __restrict__ msum, f16* __restrict__ fh,
    const float* __restrict__ W1, const float* __restrict__ b1,
    const float* __restrict__ W2, const float* __restrict__ b2)
{
    const int tid = threadIdx.x;
    const int wave = tid >> 6;       // 0..3
    const int lane = tid & 63;
    const int l16 = lane & 15;
    const int lq = lane >> 4;
    const int colbase = wave * 32;

    f16x8 w1fr[4][2], w2fr[4][2];
    float b1v[2], b2v[2];
    #pragma unroll
    for (int nt = 0; nt < 2; ++nt) {
        const int col = colbase + nt * 16 + l16;
        #pragma unroll
        for (int k = 0; k < 4; ++k) {
            f16x8 v1, v2;
            #pragma unroll
            for (int j = 0; j < 8; ++j) {
                v1[j] = (f16)W1[(size_t)(k * 32 + lq * 8 + j) * H + col];
                v2[j] = (f16)W2[(size_t)(k * 32 + lq * 8 + j) * H + col];
            }
            w1fr[k][nt] = v1;
            w2fr[k][nt] = v2;
        }
        b1v[nt] = b1[col];
        b2v[nt] = b2[col];
    }

    __shared__ alignas(16) f16 U[32][136];
    for (int tile = blockIdx.x; tile < NT_N; tile += gridDim.x) {
        __syncthreads();
        const int n0 = tile * 32;
        {
            int row = tid >> 3, ch = tid & 7;   // 16 cols per thread
            int n = n0 + row;
            if (n < N_NODES) {
                const float4* pm = (const float4*)(msum + (size_t)n * H) + ch * 4;
                const f16x8*  pf = (const f16x8*)(fh + (size_t)n * H) + ch * 2;
                f16x8 f0 = pf[0], f1 = pf[1];
                float4 a0 = pm[0], a1 = pm[1], a2 = pm[2], a3 = pm[3];
                f16 tmp[16];
                tmp[0]  = (f16)(a0.x + (float)f0[0]); tmp[1]  = (f16)(a0.y + (float)f0[1]);
                tmp[2]  = (f16)(a0.z + (float)f0[2]); tmp[3]  = (f16)(a0.w + (float)f0[3]);
                tmp[4]  = (f16)(a1.x + (float)f0[4]); tmp[5]  = (f16)(a1.y + (float)f0[5]);
                tmp[6]  = (f16)(a1.z + (float)f0[6]); tmp[7]  = (f16)(a1.w + (float)f0[7]);
                tmp[8]  = (f16)(a2.x + (float)f1[0]); tmp[9]  = (f16)(a2.y + (float)f1[1]);
                tmp[10] = (f16)(a2.z + (float)f1[2]); tmp[11] = (f16)(a2.w + (float)f1[3]);
                tmp[12] = (f16)(a3.x + (float)f1[4]); tmp[13] = (f16)(a3.y + (float)f1[5]);
                tmp[14] = (f16)(a3.z + (float)f1[6]); tmp[15] = (f16)(a3.w + (float)f1[7]);
                int4* q0 = (int4*)(&U[row][ch * 16]);
                q0[0] = ((const int4*)tmp)[0];
                q0[1] = ((const int4*)tmp)[1];
            }
        }
        __syncthreads();

        f32x4 acc[2][2];
        #pragma unroll
        for (int m = 0; m < 2; ++m)
            #pragma unroll
            for (int nt = 0; nt < 2; ++nt) {
                f32x4 c = {b1v[nt], b1v[nt], b1v[nt], b1v[nt]};
                acc[m][nt] = c;
            }
        #pragma unroll
        for (int k = 0; k < 4; ++k) {
            #pragma unroll
            for (int m = 0; m < 2; ++m) {
                f16x8 a = *(const f16x8*)&U[m * 16 + l16][k * 32 + lq * 8];
                #pragma unroll
                for (int nt = 0; nt < 2; ++nt)
                    acc[m][nt] = __builtin_amdgcn_mfma_f32_16x16x32_f16(a, w1fr[k][nt], acc[m][nt], 0, 0, 0);
            }
        }
        __syncthreads();
        #pragma unroll
        for (int m = 0; m < 2; ++m)
            #pragma unroll
            for (int nt = 0; nt < 2; ++nt)
                #pragma unroll
                for (int r = 0; r < 4; ++r)
                    U[m * 16 + lq * 4 + r][colbase + nt * 16 + l16] = (f16)fmaxf(acc[m][nt][r], 0.0f);
        __syncthreads();

        f32x4 acc2[2][2];
        #pragma unroll
        for (int m = 0; m < 2; ++m)
            #pragma unroll
            for (int nt = 0; nt < 2; ++nt) {
                f32x4 c = {b2v[nt], b2v[nt], b2v[nt], b2v[nt]};
                acc2[m][nt] = c;
            }
        #pragma unroll
        for (int k = 0; k < 4; ++k) {
            #pragma unroll
            for (int m = 0; m < 2; ++m) {
                f16x8 a = *(const f16x8*)&U[m * 16 + l16][k * 32 + lq * 8];
                #pragma unroll
                for (int nt = 0; nt < 2; ++nt)
                    acc2[m][nt] = __builtin_amdgcn_mfma_f32_16x16x32_f16(a, w2fr[k][nt], acc2[m][nt], 0, 0, 0);
            }
        }
        #pragma unroll
        for (int m = 0; m < 2; ++m)
            #pragma unroll
            for (int nt = 0; nt < 2; ++nt)
                #pragma unroll
                for (int r = 0; r < 4; ++r) {
                    int row = m * 16 + lq * 4 + r;
                    int n = n0 + row;
                    if (n < N_NODES)
                        fh[(size_t)n * H + colbase + nt * 16 + l16] = (f16)fmaxf(acc2[m][nt][r], 0.0f);
                }
    }
}

// ---------------------------------------------------------------------------
// Per-graph mean/max readout (graph_ids sorted; f >= 0)
// ---------------------------------------------------------------------------
__global__ void k_readout(const f16* __restrict__ fh, const int* __restrict__ gid,
                          float* __restrict__ gsum, float* __restrict__ gmax,
                          int* __restrict__ gcnt)
{
    __shared__ int s_gid[64];
    const int tid = threadIdx.x;            // 128 threads
    const int base = blockIdx.x * 64;
    if (tid < 64) s_gid[tid] = (base + tid < N_NODES) ? gid[base + tid] : -1;
    __syncthreads();
    if (tid < 64 && base + tid < N_NODES) atomicAdd(&gcnt[s_gid[tid]], 1);

    float lsum = 0.0f, lmax = 0.0f;
    int cur = s_gid[0];
    if (cur >= 0) {
        for (int i = 0; i < 64; ++i) {
            int g = s_gid[i];
            if (g < 0) break;
            if (g != cur) {
                unsafeAtomicAdd(&gsum[(size_t)cur * H + tid], lsum);
                atomicMax((int*)&gmax[(size_t)cur * H + tid], __float_as_int(lmax));
                lsum = 0.0f; lmax = 0.0f; cur = g;
            }
            float v = (float)fh[(size_t)(base + i) * H + tid];
            lsum += v;
            lmax = fmaxf(lmax, v);
        }
        unsafeAtomicAdd(&gsum[(size_t)cur * H + tid], lsum);
        atomicMax((int*)&gmax[(size_t)cur * H + tid], __float_as_int(lmax));
    }
}

__global__ void k_out(const float* __restrict__ gsum, const float* __restrict__ gmax,
                      const int* __restrict__ gcnt, const float* __restrict__ W_out,
                      const float* __restrict__ b_out, float* __restrict__ out)
{
    __shared__ float sm[128], sx[128];
    const int g = blockIdx.x, t = threadIdx.x;
    const float inv = 1.0f / fmaxf((float)gcnt[g], 1.0f);
    sm[t] = gsum[(size_t)g * H + t] * inv;
    sx[t] = gmax[(size_t)g * H + t];
    __syncthreads();
    float acc = b_out[t];
    for (int k = 0; k < H; ++k) {
        acc = fmaf(sm[k], W_out[(size_t)k * 128 + t], acc);
        acc = fmaf(sx[k], W_out[(size_t)(128 + k) * 128 + t], acc);
    }
    out[(size_t)g * 128 + t] = acc;
}

// ---------------------------------------------------------------------------
extern "C" void kernel_launch(void* const* d_in, const int* in_sizes, int n_in,
                              void* d_out, int out_size, void* d_ws, size_t ws_size,
                              hipStream_t stream)
{
    const float* node_f = (const float*)d_in[0];
    const float* node_x = (const float*)d_in[1];
    const float* edge_w = (const float*)d_in[2];
    const int*   src    = (const int*)d_in[3];
    const int*   dst    = (const int*)d_in[4];
    const int*   gid    = (const int*)d_in[5];
    const float* W_in   = (const float*)d_in[6];
    const float* b_in   = (const float*)d_in[7];
    const float* W_e    = (const float*)d_in[8];
    const float* b_e    = (const float*)d_in[9];
    const float* msg_W1 = (const float*)d_in[10];
    const float* msg_b1 = (const float*)d_in[11];
    const float* msg_W2 = (const float*)d_in[12];
    const float* msg_b2 = (const float*)d_in[13];
    const float* upd_W1 = (const float*)d_in[14];
    const float* upd_b1 = (const float*)d_in[15];
    const float* upd_W2 = (const float*)d_in[16];
    const float* upd_b2 = (const float*)d_in[17];
    const float* W_out  = (const float*)d_in[18];
    const float* b_out  = (const float*)d_in[19];
    float* out = (float*)d_out;

    char* ws = (char*)d_ws;
    size_t off = 0;
    f16*   fh       = (f16*)(ws + off);   off += (size_t)N_NODES * H * 2;      // 12.8 MB
    f16*   perm_ewh = (f16*)(ws + off);   off += (size_t)N_EDGES * 16 * 2;     // 19.2 MB
    int*   perm_src = (int*)(ws + off);   off += (size_t)N_EDGES * 4;          // 2.4 MB
    int*   perm_dst = (int*)(ws + off);   off += (size_t)N_EDGES * 4;          // 2.4 MB
    float* perm_sq  = (float*)(ws + off); off += (size_t)N_EDGES * 4;          // 2.4 MB
    int*   rowptr   = (int*)(ws + off);   off += (size_t)NP * 4;
    int*   cnt      = (int*)(ws + off);   off += (size_t)NP * 4;               // also 'fill'
    int*   bsum     = (int*)(ws + off);   off += 256 * 4;
    int*   boff     = (int*)(ws + off);   off += 256 * 4;
    float* msum     = (float*)(ws + off); off += (size_t)N_NODES * H * 4;      // 25.6 MB
    float* gsum     = (float*)(ws + off); off += (size_t)G_GRAPHS * H * 4;
    float* gmax     = (float*)(ws + off); off += (size_t)G_GRAPHS * H * 4;
    int*   gcnt     = (int*)(ws + off);   off += (size_t)G_GRAPHS * 4;
    int*   perm_eidx = (int*)msum;        // aliased: eidx only used pre-layers

    k_f0<<<(N_NODES + 7) / 8, 128, 0, stream>>>(node_f, W_in, b_in, fh);

    (void)hipMemsetAsync(cnt, 0, (size_t)NP * 4, stream);
    k_hist<<<(N_EDGES + 255) / 256, 256, 0, stream>>>(dst, cnt);
    k_scanA<<<NP / 256, 256, 0, stream>>>(cnt, rowptr, bsum);
    k_scanB<<<1, 256, 0, stream>>>(bsum, boff);
    k_scanC<<<NP / 256, 256, 0, stream>>>(rowptr, boff);
    (void)hipMemsetAsync(cnt, 0, (size_t)NP * 4, stream);
    k_scatter_idx<<<(N_EDGES + 255) / 256, 256, 0, stream>>>(dst, rowptr, cnt, perm_eidx);
    k_gather<<<(N_EDGES + 255) / 256, 256, 0, stream>>>(perm_eidx, edge_w, src, dst, node_x,
                                                        perm_src, perm_dst, perm_sq, perm_ewh);

    for (int l = 0; l < 4; ++l) {
        (void)hipMemsetAsync(msum, 0, (size_t)N_NODES * H * 4, stream);
        k_edge2<<<NB_E, 512, 0, stream>>>(fh, perm_src, perm_dst, perm_sq, perm_ewh,
                                          W_e, b_e,
                                          msg_W1 + (size_t)l * 385 * H, msg_b1 + (size_t)l * H,
                                          msg_W2 + (size_t)l * H * H,  msg_b2 + (size_t)l * H,
                                          msum);
        k_update<<<512, 256, 0, stream>>>(msum, fh,
                                          upd_W1 + (size_t)l * H * H, upd_b1 + (size_t)l * H,
                                          upd_W2 + (size_t)l * H * H, upd_b2 + (size_t)l * H);
    }

    (void)hipMemsetAsync(gsum, 0, (size_t)G_GRAPHS * H * 4, stream);
    (void)hipMemsetAsync(gmax, 0, (size_t)G_GRAPHS * H * 4, stream);
    (void)hipMemsetAsync(gcnt, 0, (size_t)G_GRAPHS * 4, stream);
    k_readout<<<(N_NODES + 63) / 64, 128, 0, stream>>>(fh, gid, gsum, gmax, gcnt);
    k_out<<<G_GRAPHS, 128, 0, stream>>>(gsum, gmax, gcnt, W_out, b_out, out);
}

// Round 8
// 1476.322 us; speedup vs baseline: 2.1452x; 1.0084x over previous
//
#include <hip/hip_runtime.h>
#include <hip/hip_fp16.h>

typedef _Float16 f16;
typedef _Float16 f16x8 __attribute__((ext_vector_type(8)));
typedef float f32x4 __attribute__((ext_vector_type(4)));

#define N_NODES 50000
#define N_EDGES 600000
#define G_GRAPHS 128
#define H 128
#define NP 50176              // 196*256, padded node count for scan
#define NT_E 18750            // 600000/32 exact
#define NB_E 1024             // edge-kernel grid (8*128 for XCD remap)
#define NT_N 1563             // ceil(50000/32)

// ---------------------------------------------------------------------------
// f0 = relu(node_f @ W_in + b_in)  -> fh (f16)
// ---------------------------------------------------------------------------
__global__ void k_f0(const float* __restrict__ node_f, const float* __restrict__ W_in,
                     const float* __restrict__ b_in, f16* __restrict__ fh)
{
    __shared__ float sW[32 * 128];
    __shared__ float sx[8][32];
    const int tid = threadIdx.x;     // 128 threads
    const int base = blockIdx.x * 8;
    for (int i = tid; i < 32 * 128; i += 128) sW[i] = W_in[i];
    for (int i = tid; i < 8 * 32; i += 128) {
        int u = i >> 5, k = i & 31;
        int n = base + u;
        sx[u][k] = (n < N_NODES) ? node_f[(size_t)n * 32 + k] : 0.0f;
    }
    __syncthreads();
    const float bj = b_in[tid];
    #pragma unroll
    for (int u = 0; u < 8; ++u) {
        int n = base + u;
        if (n >= N_NODES) break;
        float acc = bj;
        #pragma unroll
        for (int k = 0; k < 32; ++k) acc = fmaf(sx[u][k], sW[k * 128 + tid], acc);
        fh[(size_t)n * H + tid] = (f16)fmaxf(acc, 0.0f);
    }
}

// ---------------------------------------------------------------------------
// CSR build: histogram, scan, idx scatter, sequential gather (dst-sorted perm)
// ---------------------------------------------------------------------------
__global__ void k_hist(const int* __restrict__ dst, int* __restrict__ cnt)
{
    int e = blockIdx.x * 256 + threadIdx.x;
    if (e < N_EDGES) atomicAdd(&cnt[dst[e]], 1);
}

__global__ void k_scanA(const int* __restrict__ cnt, int* __restrict__ rowptr,
                        int* __restrict__ bsum)
{
    __shared__ int s[256];
    const int t = threadIdx.x;
    const int i = blockIdx.x * 256 + t;
    int v = cnt[i];
    s[t] = v;
    __syncthreads();
    #pragma unroll
    for (int off = 1; off < 256; off <<= 1) {
        int x = (t >= off) ? s[t - off] : 0;
        __syncthreads();
        s[t] += x;
        __syncthreads();
    }
    rowptr[i] = s[t] - v;
    if (t == 255) bsum[blockIdx.x] = s[255];
}

__global__ void k_scanB(const int* __restrict__ bsum, int* __restrict__ boff)
{
    __shared__ int s[256];
    const int t = threadIdx.x;
    int v = (t < 196) ? bsum[t] : 0;
    s[t] = v;
    __syncthreads();
    #pragma unroll
    for (int off = 1; off < 256; off <<= 1) {
        int x = (t >= off) ? s[t - off] : 0;
        __syncthreads();
        s[t] += x;
        __syncthreads();
    }
    boff[t] = s[t] - v;
}

__global__ void k_scanC(int* __restrict__ rowptr, const int* __restrict__ boff)
{
    int i = blockIdx.x * 256 + threadIdx.x;
    rowptr[i] += boff[blockIdx.x];
}

__global__ void k_scatter_idx(const int* __restrict__ dst, const int* __restrict__ rowptr,
                              int* __restrict__ fill, int* __restrict__ perm_eidx)
{
    int e = blockIdx.x * 256 + threadIdx.x;
    if (e >= N_EDGES) return;
    int d = dst[e];
    int p = rowptr[d] + atomicAdd(&fill[d], 1);
    perm_eidx[p] = e;
}

__global__ void k_gather(const int* __restrict__ perm_eidx, const float* __restrict__ edge_w,
                         const int* __restrict__ src, const int* __restrict__ dst,
                         const float* __restrict__ node_x,
                         int* __restrict__ perm_src, int* __restrict__ perm_dst,
                         float* __restrict__ perm_sq, f16* __restrict__ perm_ewh)
{
    int pp = blockIdx.x * 256 + threadIdx.x;
    if (pp >= N_EDGES) return;
    int e = perm_eidx[pp];
    int s = src[e], d = dst[e];
    float dx = node_x[s * 3 + 0] - node_x[d * 3 + 0];
    float dy = node_x[s * 3 + 1] - node_x[d * 3 + 1];
    float dz = node_x[s * 3 + 2] - node_x[d * 3 + 2];
    perm_src[pp] = s;
    perm_dst[pp] = d;
    perm_sq[pp] = dx * dx + dy * dy + dz * dz;
    const float4* pw = (const float4*)(edge_w + (size_t)e * 16);
    float4 w0 = pw[0], w1 = pw[1], w2 = pw[2], w3 = pw[3];
    f16x8 v0, v1;
    v0[0] = (f16)w0.x; v0[1] = (f16)w0.y; v0[2] = (f16)w0.z; v0[3] = (f16)w0.w;
    v0[4] = (f16)w1.x; v0[5] = (f16)w1.y; v0[6] = (f16)w1.z; v0[7] = (f16)w1.w;
    v1[0] = (f16)w2.x; v1[1] = (f16)w2.y; v1[2] = (f16)w2.z; v1[3] = (f16)w2.w;
    v1[4] = (f16)w3.x; v1[5] = (f16)w3.y; v1[6] = (f16)w3.z; v1[7] = (f16)w3.w;
    f16x8* q = (f16x8*)(perm_ewh + (size_t)pp * 16);
    q[0] = v0; q[1] = v1;
}

// ---------------------------------------------------------------------------
// Edge-parallel message kernel, dst-sorted 32-edge tiles. 8 waves x 16 cols.
// 2 barriers/tile (h1B ping-pong); packed __half2 atomics into f16 msum.
// Hazards:
//  - Atile: written S1(t), read mm1 S2(t) [B1 between]; next write S1(t+1)
//    is after B2(t) which follows all S2(t) reads.  OK.
//  - h1B[q]: written S2(t), read S4(t) [B2 between]; next write to same q is
//    S2(t+2), separated from S4(t) reads by B1(t+1)+B2(t+1).  OK.
//  - meta[p]: read S1(t)/S2(t); overwritten by prefetch in S1(t+1) which is
//    after B2(t).  OK.
// Lane pairs (l16 even/odd, same lq) have IDENTICAL run segmentation (dc[]
// depends only on lq), so even lane packs (own run, shfl_xor(run,1)) into one
// __half2 atomic for cols (c, c+1).
// ---------------------------------------------------------------------------
__global__ __launch_bounds__(512, 2) void k_edge2(
    const f16* __restrict__ fh,
    const int* __restrict__ perm_src, const int* __restrict__ perm_dst,
    const float* __restrict__ perm_sq, const f16* __restrict__ perm_ewh,
    const float* __restrict__ W_e, const float* __restrict__ b_e,
    const float* __restrict__ W1, const float* __restrict__ b1,
    const float* __restrict__ W2, const float* __restrict__ b2,
    f16* __restrict__ msum)
{
    const int tid = threadIdx.x;
    const int wave = tid >> 6;
    const int lane = tid & 63;
    const int l16 = lane & 15;
    const int lq  = lane >> 4;
    const int col = wave * 16 + l16;

    f16x8 wef, w1f[12], w2f[4];
    #pragma unroll
    for (int j = 0; j < 8; ++j) {
        int k = lq * 8 + j;
        wef[j] = (k < 16) ? (f16)W_e[(size_t)k * H + col] : (f16)0.0f;
    }
    #pragma unroll
    for (int k = 0; k < 12; ++k)
        #pragma unroll
        for (int j = 0; j < 8; ++j)
            w1f[k][j] = (f16)W1[(size_t)(k * 32 + lq * 8 + j) * H + col];
    #pragma unroll
    for (int k = 0; k < 4; ++k)
        #pragma unroll
        for (int j = 0; j < 8; ++j)
            w2f[k][j] = (f16)W2[(size_t)(k * 32 + lq * 8 + j) * H + col];
    const float w1last = W1[(size_t)384 * H + col];
    const float b1v = b1[col], b2v = b2[col], bev = b_e[col];

    __shared__ alignas(16) f16 Atile[32][392];     // 25.1 KB
    __shared__ alignas(16) f16 h1B[2][32][136];    // 17.4 KB (ping-pong)
    __shared__ int   s_src[2][32];
    __shared__ int   s_dst[2][32];
    __shared__ float s_sq[2][32];

    // XCD-contiguous remap: XCD x (= blockIdx%8) gets ranges [x*128,(x+1)*128)
    const int b = ((blockIdx.x & 7) << 7) | (blockIdx.x >> 3);
    const int t0 = (int)((long)b * NT_E / NB_E);
    const int t1 = (int)((long)(b + 1) * NT_E / NB_E);

    if (tid < 32) {                       // prefetch meta for t0 (edge order)
        int e = t0 * 32 + tid;
        s_src[0][tid] = perm_src[e];
        s_dst[0][tid] = perm_dst[e];
        s_sq[0][tid]  = perm_sq[e];
    }
    __syncthreads();

    int p = 0, q = 0;
    for (int t = t0; t < t1; ++t, p ^= 1, q ^= 1) {
        // ---- S1: stage [f_src|f_dst] (rows permuted); we-MFMA; prefetch meta ----
        {
            int row = tid >> 4, ch = tid & 15;
            int j = ((row >> 2) & 3) * 8 + (row >> 4) * 4 + (row & 3); // eperm(row)
            int sv = s_src[p][j];
            int dv = s_dst[p][j];
            ((int4*)&Atile[row][0])[ch]   = ((const int4*)(fh + (size_t)sv * H))[ch];
            ((int4*)&Atile[row][128])[ch] = ((const int4*)(fh + (size_t)dv * H))[ch];
        }
        #pragma unroll
        for (int m = 0; m < 2; ++m) {
            f16x8 a;
            if (lq < 2) {
                int j = (l16 >> 2) * 8 + m * 4 + (l16 & 3);
                int e = t * 32 + j;
                a = *(const f16x8*)(perm_ewh + (size_t)e * 16 + lq * 8);
            } else {
                #pragma unroll
                for (int jj = 0; jj < 8; ++jj) a[jj] = (f16)0.0f;
            }
            f32x4 c = {bev, bev, bev, bev};
            c = __builtin_amdgcn_mfma_f32_16x16x32_f16(a, wef, c, 0, 0, 0);
            #pragma unroll
            for (int r = 0; r < 4; ++r)
                Atile[m * 16 + lq * 4 + r][256 + col] = (f16)fmaxf(c[r], 0.0f);
        }
        if (tid < 32 && t + 1 < t1) {
            int e = (t + 1) * 32 + tid;
            s_src[p ^ 1][tid] = perm_src[e];
            s_dst[p ^ 1][tid] = perm_dst[e];
            s_sq[p ^ 1][tid]  = perm_sq[e];
        }
        __syncthreads();   // B1

        // ---- S2: dc cache; mm1; h1 -> h1B[q] ----
        int dc[8];
        f32x4 acc1[2];
        #pragma unroll
        for (int m = 0; m < 2; ++m)
            #pragma unroll
            for (int r = 0; r < 4; ++r) {
                int j = lq * 8 + m * 4 + r;      // edge for tile row m*16+lq*4+r
                dc[m * 4 + r] = s_dst[p][j];
                acc1[m][r] = fmaf(s_sq[p][j], w1last, b1v);
            }
        #pragma unroll
        for (int k = 0; k < 12; ++k) {
            #pragma unroll
            for (int m = 0; m < 2; ++m) {
                f16x8 a = *(const f16x8*)&Atile[m * 16 + l16][k * 32 + lq * 8];
                acc1[m] = __builtin_amdgcn_mfma_f32_16x16x32_f16(a, w1f[k], acc1[m], 0, 0, 0);
            }
        }
        #pragma unroll
        for (int m = 0; m < 2; ++m)
            #pragma unroll
            for (int r = 0; r < 4; ++r)
                h1B[q][m * 16 + lq * 4 + r][col] = (f16)fmaxf(acc1[m][r], 0.0f);
        __syncthreads();   // B2

        // ---- S4: mm2; run-compressed packed-f16x2 atomic scatter ----
        f32x4 acc2[2];
        #pragma unroll
        for (int m = 0; m < 2; ++m) {
            f32x4 c = {b2v, b2v, b2v, b2v};
            acc2[m] = c;
        }
        #pragma unroll
        for (int k = 0; k < 4; ++k) {
            #pragma unroll
            for (int m = 0; m < 2; ++m) {
                f16x8 a = *(const f16x8*)&h1B[q][m * 16 + l16][k * 32 + lq * 8];
                acc2[m] = __builtin_amdgcn_mfma_f32_16x16x32_f16(a, w2f[k], acc2[m], 0, 0, 0);
            }
        }
        {
            float run = fmaxf(acc2[0][0], 0.0f);
            int cd = dc[0];
            #pragma unroll
            for (int i = 1; i < 8; ++i) {
                float v = fmaxf(acc2[i >> 2][i & 3], 0.0f);
                int d = dc[i];
                if (d == cd) {
                    run += v;
                } else {
                    float nb = __shfl_xor(run, 1);
                    if ((l16 & 1) == 0) {
                        union { f16 h[2]; __half2 v2; } u;
                        u.h[0] = (f16)run; u.h[1] = (f16)nb;
                        unsafeAtomicAdd((__half2*)&msum[(size_t)cd * H + col], u.v2);
                    }
                    run = v; cd = d;
                }
            }
            float nb = __shfl_xor(run, 1);
            if ((l16 & 1) == 0) {
                union { f16 h[2]; __half2 v2; } u;
                u.h[0] = (f16)run; u.h[1] = (f16)nb;
                unsafeAtomicAdd((__half2*)&msum[(size_t)cd * H + col], u.v2);
            }
        }
    }
}

// ---------------------------------------------------------------------------
// Node update: fh = relu(relu((msum+fh)@U1+b1)@U2+b2)   (in-place on fh)
// ---------------------------------------------------------------------------
__global__ __launch_bounds__(256, 4) void k_update(
    const f16* __restrict__ msum, f16* __restrict__ fh,
    const float* __restrict__ W1, const float* __restrict__ b1,
    const float* __restrict__ W2, const float* __restrict__ b2)
{
    const int tid = threadIdx.x;
    const int wave = tid >> 6;       // 0..3
    const int lane = tid & 63;
    const int l16 = lane & 15;
    const int lq = lane >> 4;
    const int colbase = wave * 32;

    f16x8 w1fr[4][2], w2fr[4][2];
    float b1v[2], b2v[2];
    #pragma unroll
    for (int nt = 0; nt < 2; ++nt) {
        const int col = colbase + nt * 16 + l16;
        #pragma unroll
        for (int k = 0; k < 4; ++k) {
            f16x8 v1, v2;
            #pragma unroll
            for (int j = 0; j < 8; ++j) {
                v1[j] = (f16)W1[(size_t)(k * 32 + lq * 8 + j) * H + col];
                v2[j] = (f16)W2[(size_t)(k * 32 + lq * 8 + j) * H + col];
            }
            w1fr[k][nt] = v1;
            w2fr[k][nt] = v2;
        }
        b1v[nt] = b1[col];
        b2v[nt] = b2[col];
    }

    __shared__ alignas(16) f16 U[32][136];
    for (int tile = blockIdx.x; tile < NT_N; tile += gridDim.x) {
        __syncthreads();
        const int n0 = tile * 32;
        {
            int row = tid >> 3, ch = tid & 7;   // 16 cols per thread
            int n = n0 + row;
            if (n < N_NODES) {
                const f16x8* pm = (const f16x8*)(msum + (size_t)n * H) + ch * 2;
                const f16x8* pf = (const f16x8*)(fh + (size_t)n * H) + ch * 2;
                f16x8 m0 = pm[0], m1 = pm[1];
                f16x8 f0 = pf[0], f1 = pf[1];
                f16 tmp[16];
                #pragma unroll
                for (int j = 0; j < 8; ++j) {
                    tmp[j]     = (f16)((float)m0[j] + (float)f0[j]);
                    tmp[8 + j] = (f16)((float)m1[j] + (float)f1[j]);
                }
                int4* q0 = (int4*)(&U[row][ch * 16]);
                q0[0] = ((const int4*)tmp)[0];
                q0[1] = ((const int4*)tmp)[1];
            }
        }
        __syncthreads();

        f32x4 acc[2][2];
        #pragma unroll
        for (int m = 0; m < 2; ++m)
            #pragma unroll
            for (int nt = 0; nt < 2; ++nt) {
                f32x4 c = {b1v[nt], b1v[nt], b1v[nt], b1v[nt]};
                acc[m][nt] = c;
            }
        #pragma unroll
        for (int k = 0; k < 4; ++k) {
            #pragma unroll
            for (int m = 0; m < 2; ++m) {
                f16x8 a = *(const f16x8*)&U[m * 16 + l16][k * 32 + lq * 8];
                #pragma unroll
                for (int nt = 0; nt < 2; ++nt)
                    acc[m][nt] = __builtin_amdgcn_mfma_f32_16x16x32_f16(a, w1fr[k][nt], acc[m][nt], 0, 0, 0);
            }
        }
        __syncthreads();
        #pragma unroll
        for (int m = 0; m < 2; ++m)
            #pragma unroll
            for (int nt = 0; nt < 2; ++nt)
                #pragma unroll
                for (int r = 0; r < 4; ++r)
                    U[m * 16 + lq * 4 + r][colbase + nt * 16 + l16] = (f16)fmaxf(acc[m][nt][r], 0.0f);
        __syncthreads();

        f32x4 acc2[2][2];
        #pragma unroll
        for (int m = 0; m < 2; ++m)
            #pragma unroll
            for (int nt = 0; nt < 2; ++nt) {
                f32x4 c = {b2v[nt], b2v[nt], b2v[nt], b2v[nt]};
                acc2[m][nt] = c;
            }
        #pragma unroll
        for (int k = 0; k < 4; ++k) {
            #pragma unroll
            for (int m = 0; m < 2; ++m) {
                f16x8 a = *(const f16x8*)&U[m * 16 + l16][k * 32 + lq * 8];
                #pragma unroll
                for (int nt = 0; nt < 2; ++nt)
                    acc2[m][nt] = __builtin_amdgcn_mfma_f32_16x16x32_f16(a, w2fr[k][nt], acc2[m][nt], 0, 0, 0);
            }
        }
        #pragma unroll
        for (int m = 0; m < 2; ++m)
            #pragma unroll
            for (int nt = 0; nt < 2; ++nt)
                #pragma unroll
                for (int r = 0; r < 4; ++r) {
                    int row = m * 16 + lq * 4 + r;
                    int n = n0 + row;
                    if (n < N_NODES)
                        fh[(size_t)n * H + colbase + nt * 16 + l16] = (f16)fmaxf(acc2[m][nt][r], 0.0f);
                }
    }
}

// ---------------------------------------------------------------------------
// Per-graph mean/max readout (graph_ids sorted; f >= 0)
// ---------------------------------------------------------------------------
__global__ void k_readout(const f16* __restrict__ fh, const int* __restrict__ gid,
                          float* __restrict__ gsum, float* __restrict__ gmax,
                          int* __restrict__ gcnt)
{
    __shared__ int s_gid[64];
    const int tid = threadIdx.x;            // 128 threads
    const int base = blockIdx.x * 64;
    if (tid < 64) s_gid[tid] = (base + tid < N_NODES) ? gid[base + tid] : -1;
    __syncthreads();
    if (tid < 64 && base + tid < N_NODES) atomicAdd(&gcnt[s_gid[tid]], 1);

    float lsum = 0.0f, lmax = 0.0f;
    int cur = s_gid[0];
    if (cur >= 0) {
        for (int i = 0; i < 64; ++i) {
            int g = s_gid[i];
            if (g < 0) break;
            if (g != cur) {
                unsafeAtomicAdd(&gsum[(size_t)cur * H + tid], lsum);
                atomicMax((int*)&gmax[(size_t)cur * H + tid], __float_as_int(lmax));
                lsum = 0.0f; lmax = 0.0f; cur = g;
            }
            float v = (float)fh[(size_t)(base + i) * H + tid];
            lsum += v;
            lmax = fmaxf(lmax, v);
        }
        unsafeAtomicAdd(&gsum[(size_t)cur * H + tid], lsum);
        atomicMax((int*)&gmax[(size_t)cur * H + tid], __float_as_int(lmax));
    }
}

__global__ void k_out(const float* __restrict__ gsum, const float* __restrict__ gmax,
                      const int* __restrict__ gcnt, const float* __restrict__ W_out,
                      const float* __restrict__ b_out, float* __restrict__ out)
{
    __shared__ float sm[128], sx[128];
    const int g = blockIdx.x, t = threadIdx.x;
    const float inv = 1.0f / fmaxf((float)gcnt[g], 1.0f);
    sm[t] = gsum[(size_t)g * H + t] * inv;
    sx[t] = gmax[(size_t)g * H + t];
    __syncthreads();
    float acc = b_out[t];
    for (int k = 0; k < H; ++k) {
        acc = fmaf(sm[k], W_out[(size_t)k * 128 + t], acc);
        acc = fmaf(sx[k], W_out[(size_t)(128 + k) * 128 + t], acc);
    }
    out[(size_t)g * 128 + t] = acc;
}

// ---------------------------------------------------------------------------
extern "C" void kernel_launch(void* const* d_in, const int* in_sizes, int n_in,
                              void* d_out, int out_size, void* d_ws, size_t ws_size,
                              hipStream_t stream)
{
    const float* node_f = (const float*)d_in[0];
    const float* node_x = (const float*)d_in[1];
    const float* edge_w = (const float*)d_in[2];
    const int*   src    = (const int*)d_in[3];
    const int*   dst    = (const int*)d_in[4];
    const int*   gid    = (const int*)d_in[5];
    const float* W_in   = (const float*)d_in[6];
    const float* b_in   = (const float*)d_in[7];
    const float* W_e    = (const float*)d_in[8];
    const float* b_e    = (const float*)d_in[9];
    const float* msg_W1 = (const float*)d_in[10];
    const float* msg_b1 = (const float*)d_in[11];
    const float* msg_W2 = (const float*)d_in[12];
    const float* msg_b2 = (const float*)d_in[13];
    const float* upd_W1 = (const float*)d_in[14];
    const float* upd_b1 = (const float*)d_in[15];
    const float* upd_W2 = (const float*)d_in[16];
    const float* upd_b2 = (const float*)d_in[17];
    const float* W_out  = (const float*)d_in[18];
    const float* b_out  = (const float*)d_in[19];
    float* out = (float*)d_out;

    char* ws = (char*)d_ws;
    size_t off = 0;
    f16*   fh       = (f16*)(ws + off);   off += (size_t)N_NODES * H * 2;      // 12.8 MB
    f16*   perm_ewh = (f16*)(ws + off);   off += (size_t)N_EDGES * 16 * 2;     // 19.2 MB
    int*   perm_src = (int*)(ws + off);   off += (size_t)N_EDGES * 4;          // 2.4 MB
    int*   perm_dst = (int*)(ws + off);   off += (size_t)N_EDGES * 4;          // 2.4 MB
    float* perm_sq  = (float*)(ws + off); off += (size_t)N_EDGES * 4;          // 2.4 MB
    int*   rowptr   = (int*)(ws + off);   off += (size_t)NP * 4;
    int*   cnt      = (int*)(ws + off);   off += (size_t)NP * 4;               // also 'fill'
    int*   bsum     = (int*)(ws + off);   off += 256 * 4;
    int*   boff     = (int*)(ws + off);   off += 256 * 4;
    f16*   msum     = (f16*)(ws + off);   off += (size_t)N_NODES * H * 2;      // 12.8 MB
    float* gsum     = (float*)(ws + off); off += (size_t)G_GRAPHS * H * 4;
    float* gmax     = (float*)(ws + off); off += (size_t)G_GRAPHS * H * 4;
    int*   gcnt     = (int*)(ws + off);   off += (size_t)G_GRAPHS * 4;
    int*   perm_eidx = (int*)msum;        // aliased: eidx only used pre-layers

    k_f0<<<(N_NODES + 7) / 8, 128, 0, stream>>>(node_f, W_in, b_in, fh);

    (void)hipMemsetAsync(cnt, 0, (size_t)NP * 4, stream);
    k_hist<<<(N_EDGES + 255) / 256, 256, 0, stream>>>(dst, cnt);
    k_scanA<<<NP / 256, 256, 0, stream>>>(cnt, rowptr, bsum);
    k_scanB<<<1, 256, 0, stream>>>(bsum, boff);
    k_scanC<<<NP / 256, 256, 0, stream>>>(rowptr, boff);
    (void)hipMemsetAsync(cnt, 0, (size_t)NP * 4, stream);
    k_scatter_idx<<<(N_EDGES + 255) / 256, 256, 0, stream>>>(dst, rowptr, cnt, perm_eidx);
    k_gather<<<(N_EDGES + 255) / 256, 256, 0, stream>>>(perm_eidx, edge_w, src, dst, node_x,
                                                        perm_src, perm_dst, perm_sq, perm_ewh);

    for (int l = 0; l < 4; ++l) {
        (void)hipMemsetAsync(msum, 0, (size_t)N_NODES * H * 2, stream);
        k_edge2<<<NB_E, 512, 0, stream>>>(fh, perm_src, perm_dst, perm_sq, perm_ewh,
                                          W_e, b_e,
                                          msg_W1 + (size_t)l * 385 * H, msg_b1 + (size_t)l * H,
                                          msg_W2 + (size_t)l * H * H,  msg_b2 + (size_t)l * H,
                                          msum);
        k_update<<<512, 256, 0, stream>>>(msum, fh,
                                          upd_W1 + (size_t)l * H * H, upd_b1 + (size_t)l * H,
                                          upd_W2 + (size_t)l * H * H, upd_b2 + (size_t)l * H);
    }

    (void)hipMemsetAsync(gsum, 0, (size_t)G_GRAPHS * H * 4, stream);
    (void)hipMemsetAsync(gmax, 0, (size_t)G_GRAPHS * H * 4, stream);
    (void)hipMemsetAsync(gcnt, 0, (size_t)G_GRAPHS * 4, stream);
    k_readout<<<(N_NODES + 63) / 64, 128, 0, stream>>>(fh, gid, gsum, gmax, gcnt);
    k_out<<<G_GRAPHS, 128, 0, stream>>>(gsum, gmax, gcnt, W_out, b_out, out);
}

// Round 9
// 1287.917 us; speedup vs baseline: 2.4591x; 1.1463x over previous
//
#include <hip/hip_runtime.h>
#include <hip/hip_fp16.h>

typedef _Float16 f16;
typedef _Float16 f16x8 __attribute__((ext_vector_type(8)));
typedef float f32x4 __attribute__((ext_vector_type(4)));

#define N_NODES 50000
#define N_EDGES 600000
#define G_GRAPHS 128
#define H 128
#define NP 50176              // 196*256, padded node count for scan
#define NT_E 18750            // 600000/32 exact
#define NB_E 1024             // edge-kernel grid (8*128 for XCD remap)
#define NT_N 1563             // ceil(50000/32)

// ---------------------------------------------------------------------------
// f0 = relu(node_f @ W_in + b_in)  -> fh (f16)
// ---------------------------------------------------------------------------
__global__ void k_f0(const float* __restrict__ node_f, const float* __restrict__ W_in,
                     const float* __restrict__ b_in, f16* __restrict__ fh)
{
    __shared__ float sW[32 * 128];
    __shared__ float sx[8][32];
    const int tid = threadIdx.x;     // 128 threads
    const int base = blockIdx.x * 8;
    for (int i = tid; i < 32 * 128; i += 128) sW[i] = W_in[i];
    for (int i = tid; i < 8 * 32; i += 128) {
        int u = i >> 5, k = i & 31;
        int n = base + u;
        sx[u][k] = (n < N_NODES) ? node_f[(size_t)n * 32 + k] : 0.0f;
    }
    __syncthreads();
    const float bj = b_in[tid];
    #pragma unroll
    for (int u = 0; u < 8; ++u) {
        int n = base + u;
        if (n >= N_NODES) break;
        float acc = bj;
        #pragma unroll
        for (int k = 0; k < 32; ++k) acc = fmaf(sx[u][k], sW[k * 128 + tid], acc);
        fh[(size_t)n * H + tid] = (f16)fmaxf(acc, 0.0f);
    }
}

// ---------------------------------------------------------------------------
// CSR build: histogram, scan, idx scatter, sequential gather (dst-sorted perm)
// ---------------------------------------------------------------------------
__global__ void k_hist(const int* __restrict__ dst, int* __restrict__ cnt)
{
    int e = blockIdx.x * 256 + threadIdx.x;
    if (e < N_EDGES) atomicAdd(&cnt[dst[e]], 1);
}

__global__ void k_scanA(const int* __restrict__ cnt, int* __restrict__ rowptr,
                        int* __restrict__ bsum)
{
    __shared__ int s[256];
    const int t = threadIdx.x;
    const int i = blockIdx.x * 256 + t;
    int v = cnt[i];
    s[t] = v;
    __syncthreads();
    #pragma unroll
    for (int off = 1; off < 256; off <<= 1) {
        int x = (t >= off) ? s[t - off] : 0;
        __syncthreads();
        s[t] += x;
        __syncthreads();
    }
    rowptr[i] = s[t] - v;
    if (t == 255) bsum[blockIdx.x] = s[255];
}

__global__ void k_scanB(const int* __restrict__ bsum, int* __restrict__ boff)
{
    __shared__ int s[256];
    const int t = threadIdx.x;
    int v = (t < 196) ? bsum[t] : 0;
    s[t] = v;
    __syncthreads();
    #pragma unroll
    for (int off = 1; off < 256; off <<= 1) {
        int x = (t >= off) ? s[t - off] : 0;
        __syncthreads();
        s[t] += x;
        __syncthreads();
    }
    boff[t] = s[t] - v;
}

__global__ void k_scanC(int* __restrict__ rowptr, const int* __restrict__ boff)
{
    int i = blockIdx.x * 256 + threadIdx.x;
    rowptr[i] += boff[blockIdx.x];
}

__global__ void k_scatter_idx(const int* __restrict__ dst, const int* __restrict__ rowptr,
                              int* __restrict__ fill, int* __restrict__ perm_eidx)
{
    int e = blockIdx.x * 256 + threadIdx.x;
    if (e >= N_EDGES) return;
    int d = dst[e];
    int p = rowptr[d] + atomicAdd(&fill[d], 1);
    perm_eidx[p] = e;
}

__global__ void k_gather(const int* __restrict__ perm_eidx, const float* __restrict__ edge_w,
                         const int* __restrict__ src, const int* __restrict__ dst,
                         const float* __restrict__ node_x,
                         int* __restrict__ perm_src, int* __restrict__ perm_dst,
                         float* __restrict__ perm_sq, f16* __restrict__ perm_ewh)
{
    int pp = blockIdx.x * 256 + threadIdx.x;
    if (pp >= N_EDGES) return;
    int e = perm_eidx[pp];
    int s = src[e], d = dst[e];
    float dx = node_x[s * 3 + 0] - node_x[d * 3 + 0];
    float dy = node_x[s * 3 + 1] - node_x[d * 3 + 1];
    float dz = node_x[s * 3 + 2] - node_x[d * 3 + 2];
    perm_src[pp] = s;
    perm_dst[pp] = d;
    perm_sq[pp] = dx * dx + dy * dy + dz * dz;
    const float4* pw = (const float4*)(edge_w + (size_t)e * 16);
    float4 w0 = pw[0], w1 = pw[1], w2 = pw[2], w3 = pw[3];
    f16x8 v0, v1;
    v0[0] = (f16)w0.x; v0[1] = (f16)w0.y; v0[2] = (f16)w0.z; v0[3] = (f16)w0.w;
    v0[4] = (f16)w1.x; v0[5] = (f16)w1.y; v0[6] = (f16)w1.z; v0[7] = (f16)w1.w;
    v1[0] = (f16)w2.x; v1[1] = (f16)w2.y; v1[2] = (f16)w2.z; v1[3] = (f16)w2.w;
    v1[4] = (f16)w3.x; v1[5] = (f16)w3.y; v1[6] = (f16)w3.z; v1[7] = (f16)w3.w;
    f16x8* q = (f16x8*)(perm_ewh + (size_t)pp * 16);
    q[0] = v0; q[1] = v1;
}

// ---------------------------------------------------------------------------
// Edge-parallel message kernel, dst-sorted 32-edge tiles, SOFTWARE-PIPELINED:
// all global loads for tile t+1 are issued during tile t's mm1/mm2 and
// consumed (ds_write / MFMA) one barrier-section later, so no barrier drains
// a fresh load.  2 barriers/tile.
// Pipeline state entering iter t: Atile holds fs/fd(t); rew = ewh(t);
// meta[P] = meta(t) in LDS; mr_* = meta(t+1) in regs (tid<32).
// Hazards:
//  - Atile fs/fd: written step h(t-1) [after B2(t-1)], read mm1 d(t) [after
//    B1(t)]; next write h(t) after B2(t).  OK.
//  - Atile w-cols: written a(t), read d(t) [B1 between]; prev tile's w-col
//    reads ended before B2(t-1).  OK.
//  - h1B[Q]: write e(t), read g(t) [B2 between]; rewritten e(t+2) with
//    B1(t+1)+B2(t+1) in between.  OK.
//  - meta[P^1]: written b(t), read d(t) (staging addrs) and d(t+1) (dc/sq);
//    rewritten b(t+2), separated from d(t+1) by B2(t+1).  OK.
//  - register carries (rs_,rd_,rew,mr_*) are wave-private.  OK.
// ---------------------------------------------------------------------------
__global__ __launch_bounds__(512, 2) void k_edge2(
    const f16* __restrict__ fh,
    const int* __restrict__ perm_src, const int* __restrict__ perm_dst,
    const float* __restrict__ perm_sq, const f16* __restrict__ perm_ewh,
    const float* __restrict__ W_e, const float* __restrict__ b_e,
    const float* __restrict__ W1, const float* __restrict__ b1,
    const float* __restrict__ W2, const float* __restrict__ b2,
    f16* __restrict__ msum)
{
    const int tid = threadIdx.x;
    const int wave = tid >> 6;
    const int lane = tid & 63;
    const int l16 = lane & 15;
    const int lq  = lane >> 4;
    const int col = wave * 16 + l16;

    f16x8 wef, w1f[12], w2f[4];
    #pragma unroll
    for (int j = 0; j < 8; ++j) {
        int k = lq * 8 + j;
        wef[j] = (k < 16) ? (f16)W_e[(size_t)k * H + col] : (f16)0.0f;
    }
    #pragma unroll
    for (int k = 0; k < 12; ++k)
        #pragma unroll
        for (int j = 0; j < 8; ++j)
            w1f[k][j] = (f16)W1[(size_t)(k * 32 + lq * 8 + j) * H + col];
    #pragma unroll
    for (int k = 0; k < 4; ++k)
        #pragma unroll
        for (int j = 0; j < 8; ++j)
            w2f[k][j] = (f16)W2[(size_t)(k * 32 + lq * 8 + j) * H + col];
    const float w1last = W1[(size_t)384 * H + col];
    const float b1v = b1[col], b2v = b2[col], bev = b_e[col];

    __shared__ alignas(16) f16 Atile[32][392];     // 25.1 KB
    __shared__ alignas(16) f16 h1B[2][32][136];    // 17.4 KB
    __shared__ int   s_src[2][32];
    __shared__ int   s_dst[2][32];
    __shared__ float s_sq[2][32];

    // XCD-contiguous remap: XCD x (= blockIdx%8) owns ranges [x*128,(x+1)*128)
    const int b = ((blockIdx.x & 7) << 7) | (blockIdx.x >> 3);
    const int t0 = (int)((long)b * NT_E / NB_E);
    const int t1 = (int)((long)(b + 1) * NT_E / NB_E);

    const int srow = tid >> 4, sch = tid & 15;      // staging coords
    const int sj = ((srow >> 2) & 3) * 8 + ((srow >> 4) << 2) + (srow & 3); // eperm

    // ---- prologue: meta(t0) -> LDS; stage fs/fd(t0); rew(t0); mr = meta(t0+1)
    if (tid < 32) {
        int e = t0 * 32 + tid;
        s_src[0][tid] = perm_src[e];
        s_dst[0][tid] = perm_dst[e];
        s_sq[0][tid]  = perm_sq[e];
    }
    __syncthreads();
    int4 rs_, rd_;
    {
        int sv = s_src[0][sj], dv = s_dst[0][sj];
        rs_ = ((const int4*)(fh + (size_t)sv * H))[sch];
        rd_ = ((const int4*)(fh + (size_t)dv * H))[sch];
    }
    f16x8 rew[2];
    #pragma unroll
    for (int m = 0; m < 2; ++m) {
        if (lq < 2) {
            int j = (l16 >> 2) * 8 + m * 4 + (l16 & 3);
            rew[m] = *(const f16x8*)(perm_ewh + (size_t)(t0 * 32 + j) * 16 + lq * 8);
        }
    }
    int mr_s = 0, mr_d = 0; float mr_q = 0.0f;
    if (tid < 32) {
        int e = min((t0 + 1) * 32 + tid, N_EDGES - 1);
        mr_s = perm_src[e]; mr_d = perm_dst[e]; mr_q = perm_sq[e];
    }
    ((int4*)&Atile[srow][0])[sch]   = rs_;
    ((int4*)&Atile[srow][128])[sch] = rd_;

    int P = 0, Q = 0;
    for (int t = t0; t < t1; ++t, P ^= 1, Q ^= 1) {
        // a) we-MFMA(t) -> Atile w cols
        #pragma unroll
        for (int m = 0; m < 2; ++m) {
            f16x8 a;
            if (lq < 2) {
                a = rew[m];
            } else {
                #pragma unroll
                for (int jj = 0; jj < 8; ++jj) a[jj] = (f16)0.0f;
            }
            f32x4 c = {bev, bev, bev, bev};
            c = __builtin_amdgcn_mfma_f32_16x16x32_f16(a, wef, c, 0, 0, 0);
            #pragma unroll
            for (int r = 0; r < 4; ++r)
                Atile[m * 16 + lq * 4 + r][256 + col] = (f16)fmaxf(c[r], 0.0f);
        }
        // b) meta(t+1) regs -> LDS (loads issued one iter ago)
        if (tid < 32) {
            s_src[P ^ 1][tid] = mr_s;
            s_dst[P ^ 1][tid] = mr_d;
            s_sq[P ^ 1][tid]  = mr_q;
        }
        __syncthreads();   // B1

        // d) cache dc/sq; ISSUE all loads for t+1; mm1(t)
        int dc[8];
        f32x4 acc1[2];
        #pragma unroll
        for (int m = 0; m < 2; ++m)
            #pragma unroll
            for (int r = 0; r < 4; ++r) {
                int j = lq * 8 + m * 4 + r;
                dc[m * 4 + r] = s_dst[P][j];
                acc1[m][r] = fmaf(s_sq[P][j], w1last, b1v);
            }
        if (t + 1 < t1) {
            int sv = s_src[P ^ 1][sj], dv = s_dst[P ^ 1][sj];
            rs_ = ((const int4*)(fh + (size_t)sv * H))[sch];
            rd_ = ((const int4*)(fh + (size_t)dv * H))[sch];
            #pragma unroll
            for (int m = 0; m < 2; ++m) {
                if (lq < 2) {
                    int j = (l16 >> 2) * 8 + m * 4 + (l16 & 3);
                    rew[m] = *(const f16x8*)(perm_ewh + (size_t)((t + 1) * 32 + j) * 16 + lq * 8);
                }
            }
        }
        if (tid < 32) {
            int e = min((t + 2) * 32 + tid, N_EDGES - 1);
            mr_s = perm_src[e]; mr_d = perm_dst[e]; mr_q = perm_sq[e];
        }
        #pragma unroll
        for (int k = 0; k < 12; ++k) {
            #pragma unroll
            for (int m = 0; m < 2; ++m) {
                f16x8 a = *(const f16x8*)&Atile[m * 16 + l16][k * 32 + lq * 8];
                acc1[m] = __builtin_amdgcn_mfma_f32_16x16x32_f16(a, w1f[k], acc1[m], 0, 0, 0);
            }
        }
        // e) h1 -> h1B[Q]
        #pragma unroll
        for (int m = 0; m < 2; ++m)
            #pragma unroll
            for (int r = 0; r < 4; ++r)
                h1B[Q][m * 16 + lq * 4 + r][col] = (f16)fmaxf(acc1[m][r], 0.0f);
        __syncthreads();   // B2

        // g) mm2(t) + run-compressed packed-f16x2 atomics
        f32x4 acc2[2];
        #pragma unroll
        for (int m = 0; m < 2; ++m) {
            f32x4 c = {b2v, b2v, b2v, b2v};
            acc2[m] = c;
        }
        #pragma unroll
        for (int k = 0; k < 4; ++k) {
            #pragma unroll
            for (int m = 0; m < 2; ++m) {
                f16x8 a = *(const f16x8*)&h1B[Q][m * 16 + l16][k * 32 + lq * 8];
                acc2[m] = __builtin_amdgcn_mfma_f32_16x16x32_f16(a, w2f[k], acc2[m], 0, 0, 0);
            }
        }
        {
            float run = fmaxf(acc2[0][0], 0.0f);
            int cd = dc[0];
            #pragma unroll
            for (int i = 1; i < 8; ++i) {
                float v = fmaxf(acc2[i >> 2][i & 3], 0.0f);
                int d = dc[i];
                if (d == cd) {
                    run += v;
                } else {
                    float nb = __shfl_xor(run, 1);
                    if ((l16 & 1) == 0) {
                        union { f16 h[2]; __half2 v2; } u;
                        u.h[0] = (f16)run; u.h[1] = (f16)nb;
                        unsafeAtomicAdd((__half2*)&msum[(size_t)cd * H + col], u.v2);
                    }
                    run = v; cd = d;
                }
            }
            float nb = __shfl_xor(run, 1);
            if ((l16 & 1) == 0) {
                union { f16 h[2]; __half2 v2; } u;
                u.h[0] = (f16)run; u.h[1] = (f16)nb;
                unsafeAtomicAdd((__half2*)&msum[(size_t)cd * H + col], u.v2);
            }
        }
        // h) staged regs -> Atile (Atile free after B2)
        if (t + 1 < t1) {
            ((int4*)&Atile[srow][0])[sch]   = rs_;
            ((int4*)&Atile[srow][128])[sch] = rd_;
        }
    }
}

// ---------------------------------------------------------------------------
// Node update: fh = relu(relu((msum+fh)@U1+b1)@U2+b2), pipelined, 2 barriers.
// ---------------------------------------------------------------------------
__global__ __launch_bounds__(256, 3) void k_update(
    const f16* __restrict__ msum, f16* __restrict__ fh,
    const float* __restrict__ W1, const float* __restrict__ b1,
    const float* __restrict__ W2, const float* __restrict__ b2)
{
    const int tid = threadIdx.x;
    const int wave = tid >> 6;       // 0..3
    const int lane = tid & 63;
    const int l16 = lane & 15;
    const int lq = lane >> 4;
    const int colbase = wave * 32;

    f16x8 w1fr[4][2], w2fr[4][2];
    float b1v[2], b2v[2];
    #pragma unroll
    for (int nt = 0; nt < 2; ++nt) {
        const int col = colbase + nt * 16 + l16;
        #pragma unroll
        for (int k = 0; k < 4; ++k) {
            f16x8 v1, v2;
            #pragma unroll
            for (int j = 0; j < 8; ++j) {
                v1[j] = (f16)W1[(size_t)(k * 32 + lq * 8 + j) * H + col];
                v2[j] = (f16)W2[(size_t)(k * 32 + lq * 8 + j) * H + col];
            }
            w1fr[k][nt] = v1;
            w2fr[k][nt] = v2;
        }
        b1v[nt] = b1[col];
        b2v[nt] = b2[col];
    }

    __shared__ alignas(16) f16 U[32][136];
    __shared__ alignas(16) f16 h1b[32][136];
    const int row = tid >> 3, ch = tid & 7;   // staging: 32 rows x 8 int4

    int tile = blockIdx.x;
    f16x8 rm0, rm1, rf0, rf1;
    if (tile < NT_N) {
        int n = min(tile * 32 + row, N_NODES - 1);
        const f16x8* pm = (const f16x8*)(msum + (size_t)n * H) + ch * 2;
        const f16x8* pf = (const f16x8*)(fh + (size_t)n * H) + ch * 2;
        rm0 = pm[0]; rm1 = pm[1]; rf0 = pf[0]; rf1 = pf[1];
    }
    for (; tile < NT_N; tile += gridDim.x) {
        const int n0 = tile * 32;
        {   // stage-write U from regs (loaded last iter / prologue)
            f16 tmp[16];
            #pragma unroll
            for (int j = 0; j < 8; ++j) {
                tmp[j]     = (f16)((float)rm0[j] + (float)rf0[j]);
                tmp[8 + j] = (f16)((float)rm1[j] + (float)rf1[j]);
            }
            int4* q0 = (int4*)(&U[row][ch * 16]);
            q0[0] = ((const int4*)tmp)[0];
            q0[1] = ((const int4*)tmp)[1];
        }
        {   // issue next tile's loads
            int nt_ = tile + gridDim.x;
            if (nt_ < NT_N) {
                int n = min(nt_ * 32 + row, N_NODES - 1);
                const f16x8* pm = (const f16x8*)(msum + (size_t)n * H) + ch * 2;
                const f16x8* pf = (const f16x8*)(fh + (size_t)n * H) + ch * 2;
                rm0 = pm[0]; rm1 = pm[1]; rf0 = pf[0]; rf1 = pf[1];
            }
        }
        __syncthreads();   // B1

        f32x4 acc[2][2];
        #pragma unroll
        for (int m = 0; m < 2; ++m)
            #pragma unroll
            for (int nt = 0; nt < 2; ++nt) {
                f32x4 c = {b1v[nt], b1v[nt], b1v[nt], b1v[nt]};
                acc[m][nt] = c;
            }
        #pragma unroll
        for (int k = 0; k < 4; ++k) {
            #pragma unroll
            for (int m = 0; m < 2; ++m) {
                f16x8 a = *(const f16x8*)&U[m * 16 + l16][k * 32 + lq * 8];
                #pragma unroll
                for (int nt = 0; nt < 2; ++nt)
                    acc[m][nt] = __builtin_amdgcn_mfma_f32_16x16x32_f16(a, w1fr[k][nt], acc[m][nt], 0, 0, 0);
            }
        }
        #pragma unroll
        for (int m = 0; m < 2; ++m)
            #pragma unroll
            for (int nt = 0; nt < 2; ++nt)
                #pragma unroll
                for (int r = 0; r < 4; ++r)
                    h1b[m * 16 + lq * 4 + r][colbase + nt * 16 + l16] = (f16)fmaxf(acc[m][nt][r], 0.0f);
        __syncthreads();   // B2

        f32x4 acc2[2][2];
        #pragma unroll
        for (int m = 0; m < 2; ++m)
            #pragma unroll
            for (int nt = 0; nt < 2; ++nt) {
                f32x4 c = {b2v[nt], b2v[nt], b2v[nt], b2v[nt]};
                acc2[m][nt] = c;
            }
        #pragma unroll
        for (int k = 0; k < 4; ++k) {
            #pragma unroll
            for (int m = 0; m < 2; ++m) {
                f16x8 a = *(const f16x8*)&h1b[m * 16 + l16][k * 32 + lq * 8];
                #pragma unroll
                for (int nt = 0; nt < 2; ++nt)
                    acc2[m][nt] = __builtin_amdgcn_mfma_f32_16x16x32_f16(a, w2fr[k][nt], acc2[m][nt], 0, 0, 0);
            }
        }
        #pragma unroll
        for (int m = 0; m < 2; ++m)
            #pragma unroll
            for (int nt = 0; nt < 2; ++nt)
                #pragma unroll
                for (int r = 0; r < 4; ++r) {
                    int rr = m * 16 + lq * 4 + r;
                    int n = n0 + rr;
                    if (n < N_NODES)
                        fh[(size_t)n * H + colbase + nt * 16 + l16] = (f16)fmaxf(acc2[m][nt][r], 0.0f);
                }
    }
}

// ---------------------------------------------------------------------------
// Per-graph mean/max readout (graph_ids sorted; f >= 0)
// ---------------------------------------------------------------------------
__global__ void k_readout(const f16* __restrict__ fh, const int* __restrict__ gid,
                          float* __restrict__ gsum, float* __restrict__ gmax,
                          int* __restrict__ gcnt)
{
    __shared__ int s_gid[64];
    const int tid = threadIdx.x;            // 128 threads
    const int base = blockIdx.x * 64;
    if (tid < 64) s_gid[tid] = (base + tid < N_NODES) ? gid[base + tid] : -1;
    __syncthreads();
    if (tid < 64 && base + tid < N_NODES) atomicAdd(&gcnt[s_gid[tid]], 1);

    float lsum = 0.0f, lmax = 0.0f;
    int cur = s_gid[0];
    if (cur >= 0) {
        for (int i = 0; i < 64; ++i) {
            int g = s_gid[i];
            if (g < 0) break;
            if (g != cur) {
                unsafeAtomicAdd(&gsum[(size_t)cur * H + tid], lsum);
                atomicMax((int*)&gmax[(size_t)cur * H + tid], __float_as_int(lmax));
                lsum = 0.0f; lmax = 0.0f; cur = g;
            }
            float v = (float)fh[(size_t)(base + i) * H + tid];
            lsum += v;
            lmax = fmaxf(lmax, v);
        }
        unsafeAtomicAdd(&gsum[(size_t)cur * H + tid], lsum);
        atomicMax((int*)&gmax[(size_t)cur * H + tid], __float_as_int(lmax));
    }
}

__global__ void k_out(const float* __restrict__ gsum, const float* __restrict__ gmax,
                      const int* __restrict__ gcnt, const float* __restrict__ W_out,
                      const float* __restrict__ b_out, float* __restrict__ out)
{
    __shared__ float sm[128], sx[128];
    const int g = blockIdx.x, t = threadIdx.x;
    const float inv = 1.0f / fmaxf((float)gcnt[g], 1.0f);
    sm[t] = gsum[(size_t)g * H + t] * inv;
    sx[t] = gmax[(size_t)g * H + t];
    __syncthreads();
    float acc = b_out[t];
    for (int k = 0; k < H; ++k) {
        acc = fmaf(sm[k], W_out[(size_t)k * 128 + t], acc);
        acc = fmaf(sx[k], W_out[(size_t)(128 + k) * 128 + t], acc);
    }
    out[(size_t)g * 128 + t] = acc;
}

// ---------------------------------------------------------------------------
extern "C" void kernel_launch(void* const* d_in, const int* in_sizes, int n_in,
                              void* d_out, int out_size, void* d_ws, size_t ws_size,
                              hipStream_t stream)
{
    const float* node_f = (const float*)d_in[0];
    const float* node_x = (const float*)d_in[1];
    const float* edge_w = (const float*)d_in[2];
    const int*   src    = (const int*)d_in[3];
    const int*   dst    = (const int*)d_in[4];
    const int*   gid    = (const int*)d_in[5];
    const float* W_in   = (const float*)d_in[6];
    const float* b_in   = (const float*)d_in[7];
    const float* W_e    = (const float*)d_in[8];
    const float* b_e    = (const float*)d_in[9];
    const float* msg_W1 = (const float*)d_in[10];
    const float* msg_b1 = (const float*)d_in[11];
    const float* msg_W2 = (const float*)d_in[12];
    const float* msg_b2 = (const float*)d_in[13];
    const float* upd_W1 = (const float*)d_in[14];
    const float* upd_b1 = (const float*)d_in[15];
    const float* upd_W2 = (const float*)d_in[16];
    const float* upd_b2 = (const float*)d_in[17];
    const float* W_out  = (const float*)d_in[18];
    const float* b_out  = (const float*)d_in[19];
    float* out = (float*)d_out;

    char* ws = (char*)d_ws;
    size_t off = 0;
    f16*   fh       = (f16*)(ws + off);   off += (size_t)N_NODES * H * 2;      // 12.8 MB
    f16*   perm_ewh = (f16*)(ws + off);   off += (size_t)N_EDGES * 16 * 2;     // 19.2 MB
    int*   perm_src = (int*)(ws + off);   off += (size_t)N_EDGES * 4;          // 2.4 MB
    int*   perm_dst = (int*)(ws + off);   off += (size_t)N_EDGES * 4;          // 2.4 MB
    float* perm_sq  = (float*)(ws + off); off += (size_t)N_EDGES * 4;          // 2.4 MB
    int*   rowptr   = (int*)(ws + off);   off += (size_t)NP * 4;
    int*   cnt      = (int*)(ws + off);   off += (size_t)NP * 4;               // also 'fill'
    int*   bsum     = (int*)(ws + off);   off += 256 * 4;
    int*   boff     = (int*)(ws + off);   off += 256 * 4;
    f16*   msum     = (f16*)(ws + off);   off += (size_t)N_NODES * H * 2;      // 12.8 MB
    float* gsum     = (float*)(ws + off); off += (size_t)G_GRAPHS * H * 4;
    float* gmax     = (float*)(ws + off); off += (size_t)G_GRAPHS * H * 4;
    int*   gcnt     = (int*)(ws + off);   off += (size_t)G_GRAPHS * 4;
    int*   perm_eidx = (int*)msum;        // aliased: eidx only used pre-layers

    k_f0<<<(N_NODES + 7) / 8, 128, 0, stream>>>(node_f, W_in, b_in, fh);

    (void)hipMemsetAsync(cnt, 0, (size_t)NP * 4, stream);
    k_hist<<<(N_EDGES + 255) / 256, 256, 0, stream>>>(dst, cnt);
    k_scanA<<<NP / 256, 256, 0, stream>>>(cnt, rowptr, bsum);
    k_scanB<<<1, 256, 0, stream>>>(bsum, boff);
    k_scanC<<<NP / 256, 256, 0, stream>>>(rowptr, boff);
    (void)hipMemsetAsync(cnt, 0, (size_t)NP * 4, stream);
    k_scatter_idx<<<(N_EDGES + 255) / 256, 256, 0, stream>>>(dst, rowptr, cnt, perm_eidx);
    k_gather<<<(N_EDGES + 255) / 256, 256, 0, stream>>>(perm_eidx, edge_w, src, dst, node_x,
                                                        perm_src, perm_dst, perm_sq, perm_ewh);

    for (int l = 0; l < 4; ++l) {
        (void)hipMemsetAsync(msum, 0, (size_t)N_NODES * H * 2, stream);
        k_edge2<<<NB_E, 512, 0, stream>>>(fh, perm_src, perm_dst, perm_sq, perm_ewh,
                                          W_e, b_e,
                                          msg_W1 + (size_t)l * 385 * H, msg_b1 + (size_t)l * H,
                                          msg_W2 + (size_t)l * H * H,  msg_b2 + (size_t)l * H,
                                          msum);
        k_update<<<512, 256, 0, stream>>>(msum, fh,
                                          upd_W1 + (size_t)l * H * H, upd_b1 + (size_t)l * H,
                                          upd_W2 + (size_t)l * H * H, upd_b2 + (size_t)l * H);
    }

    (void)hipMemsetAsync(gsum, 0, (size_t)G_GRAPHS * H * 4, stream);
    (void)hipMemsetAsync(gmax, 0, (size_t)G_GRAPHS * H * 4, stream);
    (void)hipMemsetAsync(gcnt, 0, (size_t)G_GRAPHS * 4, stream);
    k_readout<<<(N_NODES + 63) / 64, 128, 0, stream>>>(fh, gid, gsum, gmax, gcnt);
    k_out<<<G_GRAPHS, 128, 0, stream>>>(gsum, gmax, gcnt, W_out, b_out, out);
}

// Round 10
// 1181.683 us; speedup vs baseline: 2.6801x; 1.0899x over previous
//
#include <hip/hip_runtime.h>
#include <hip/hip_fp16.h>

typedef _Float16 f16;
typedef _Float16 f16x8 __attribute__((ext_vector_type(8)));
typedef float f32x4 __attribute__((ext_vector_type(4)));

#define N_NODES 50000
#define N_EDGES 600000
#define G_GRAPHS 128
#define H 128
#define NP 50176              // 196*256, padded node count for scan
#define NT_E 18750            // 600000/32 exact
#define NB_E 1024             // edge-kernel grid (8*128 for XCD remap)
#define NT_N 1563             // ceil(50000/32)

// ---------------------------------------------------------------------------
// f0 = relu(node_f @ W_in + b_in)  -> fh (f16)
// ---------------------------------------------------------------------------
__global__ void k_f0(const float* __restrict__ node_f, const float* __restrict__ W_in,
                     const float* __restrict__ b_in, f16* __restrict__ fh)
{
    __shared__ float sW[32 * 128];
    __shared__ float sx[8][32];
    const int tid = threadIdx.x;     // 128 threads
    const int base = blockIdx.x * 8;
    for (int i = tid; i < 32 * 128; i += 128) sW[i] = W_in[i];
    for (int i = tid; i < 8 * 32; i += 128) {
        int u = i >> 5, k = i & 31;
        int n = base + u;
        sx[u][k] = (n < N_NODES) ? node_f[(size_t)n * 32 + k] : 0.0f;
    }
    __syncthreads();
    const float bj = b_in[tid];
    #pragma unroll
    for (int u = 0; u < 8; ++u) {
        int n = base + u;
        if (n >= N_NODES) break;
        float acc = bj;
        #pragma unroll
        for (int k = 0; k < 32; ++k) acc = fmaf(sx[u][k], sW[k * 128 + tid], acc);
        fh[(size_t)n * H + tid] = (f16)fmaxf(acc, 0.0f);
    }
}

// ---------------------------------------------------------------------------
// CSR build: histogram, scan, idx scatter, sequential gather (dst-sorted perm)
// ---------------------------------------------------------------------------
__global__ void k_hist(const int* __restrict__ dst, int* __restrict__ cnt)
{
    int e = blockIdx.x * 256 + threadIdx.x;
    if (e < N_EDGES) atomicAdd(&cnt[dst[e]], 1);
}

__global__ void k_scanA(const int* __restrict__ cnt, int* __restrict__ rowptr,
                        int* __restrict__ bsum)
{
    __shared__ int s[256];
    const int t = threadIdx.x;
    const int i = blockIdx.x * 256 + t;
    int v = cnt[i];
    s[t] = v;
    __syncthreads();
    #pragma unroll
    for (int off = 1; off < 256; off <<= 1) {
        int x = (t >= off) ? s[t - off] : 0;
        __syncthreads();
        s[t] += x;
        __syncthreads();
    }
    rowptr[i] = s[t] - v;
    if (t == 255) bsum[blockIdx.x] = s[255];
}

__global__ void k_scanB(const int* __restrict__ bsum, int* __restrict__ boff)
{
    __shared__ int s[256];
    const int t = threadIdx.x;
    int v = (t < 196) ? bsum[t] : 0;
    s[t] = v;
    __syncthreads();
    #pragma unroll
    for (int off = 1; off < 256; off <<= 1) {
        int x = (t >= off) ? s[t - off] : 0;
        __syncthreads();
        s[t] += x;
        __syncthreads();
    }
    boff[t] = s[t] - v;
}

__global__ void k_scanC(int* __restrict__ rowptr, const int* __restrict__ boff)
{
    int i = blockIdx.x * 256 + threadIdx.x;
    rowptr[i] += boff[blockIdx.x];
}

__global__ void k_scatter_idx(const int* __restrict__ dst, const int* __restrict__ rowptr,
                              int* __restrict__ fill, int* __restrict__ perm_eidx)
{
    int e = blockIdx.x * 256 + threadIdx.x;
    if (e >= N_EDGES) return;
    int d = dst[e];
    int p = rowptr[d] + atomicAdd(&fill[d], 1);
    perm_eidx[p] = e;
}

__global__ void k_gather(const int* __restrict__ perm_eidx, const float* __restrict__ edge_w,
                         const int* __restrict__ src, const int* __restrict__ dst,
                         const float* __restrict__ node_x,
                         int* __restrict__ perm_src, int* __restrict__ perm_dst,
                         float* __restrict__ perm_sq, f16* __restrict__ perm_ewh)
{
    int pp = blockIdx.x * 256 + threadIdx.x;
    if (pp >= N_EDGES) return;
    int e = perm_eidx[pp];
    int s = src[e], d = dst[e];
    float dx = node_x[s * 3 + 0] - node_x[d * 3 + 0];
    float dy = node_x[s * 3 + 1] - node_x[d * 3 + 1];
    float dz = node_x[s * 3 + 2] - node_x[d * 3 + 2];
    perm_src[pp] = s;
    perm_dst[pp] = d;
    perm_sq[pp] = dx * dx + dy * dy + dz * dz;
    const float4* pw = (const float4*)(edge_w + (size_t)e * 16);
    float4 w0 = pw[0], w1 = pw[1], w2 = pw[2], w3 = pw[3];
    f16x8 v0, v1;
    v0[0] = (f16)w0.x; v0[1] = (f16)w0.y; v0[2] = (f16)w0.z; v0[3] = (f16)w0.w;
    v0[4] = (f16)w1.x; v0[5] = (f16)w1.y; v0[6] = (f16)w1.z; v0[7] = (f16)w1.w;
    v1[0] = (f16)w2.x; v1[1] = (f16)w2.y; v1[2] = (f16)w2.z; v1[3] = (f16)w2.w;
    v1[4] = (f16)w3.x; v1[5] = (f16)w3.y; v1[6] = (f16)w3.z; v1[7] = (f16)w3.w;
    f16x8* q = (f16x8*)(perm_ewh + (size_t)pp * 16);
    q[0] = v0; q[1] = v1;
}

// ---------------------------------------------------------------------------
// Edge-parallel message kernel, dst-sorted 32-edge tiles, ONE barrier/tile.
// Section t: dc/sq(t) -> issue loads(t+1)+meta(t+2) -> mm2(t-1)+atomics(t-1)
//            -> mm1(t)->h1B[t&1] -> weMFMA(t+1)+stage(t+1)->Atile[(t+1)&1]
//            -> meta(t+2)->LDS -> barrier.
// Every global load/atomic has ~a full mm-section before its consuming
// waitcnt / barrier drain.
// Hazards (all cross exactly one barrier):
//  - Atile[(t+1)&1]: written late section t; read mm1 section t+1; its prior
//    reads were mm1(t-1), finished before barrier(t-1).
//  - h1B[t&1]: written section t (mm1), read section t+1 (mm2 of t); not
//    touched otherwise.
//  - meta slots (t)%3,(t+1)%3 read in section t; (t+2)%3 written in section t
//    (distinct mod 3); slot (t+2)%3 was last read in section t-1 (= (t-1)%3... 
//    (t+2)≡(t-1) mod 3), barrier between.
//  - dc carried in registers (wave-private) for the t-1 atomics.
// ---------------------------------------------------------------------------
__global__ __launch_bounds__(512, 2) void k_edge2(
    const f16* __restrict__ fh,
    const int* __restrict__ perm_src, const int* __restrict__ perm_dst,
    const float* __restrict__ perm_sq, const f16* __restrict__ perm_ewh,
    const float* __restrict__ W_e, const float* __restrict__ b_e,
    const float* __restrict__ W1, const float* __restrict__ b1,
    const float* __restrict__ W2, const float* __restrict__ b2,
    f16* __restrict__ msum)
{
    const int tid = threadIdx.x;
    const int wave = tid >> 6;
    const int lane = tid & 63;
    const int l16 = lane & 15;
    const int lq  = lane >> 4;
    const int col = wave * 16 + l16;

    f16x8 wef, w1f[12], w2f[4];
    #pragma unroll
    for (int j = 0; j < 8; ++j) {
        int k = lq * 8 + j;
        wef[j] = (k < 16) ? (f16)W_e[(size_t)k * H + col] : (f16)0.0f;
    }
    #pragma unroll
    for (int k = 0; k < 12; ++k)
        #pragma unroll
        for (int j = 0; j < 8; ++j)
            w1f[k][j] = (f16)W1[(size_t)(k * 32 + lq * 8 + j) * H + col];
    #pragma unroll
    for (int k = 0; k < 4; ++k)
        #pragma unroll
        for (int j = 0; j < 8; ++j)
            w2f[k][j] = (f16)W2[(size_t)(k * 32 + lq * 8 + j) * H + col];
    const float w1last = W1[(size_t)384 * H + col];
    const float b1v = b1[col], b2v = b2[col], bev = b_e[col];

    __shared__ alignas(16) f16 Atile[2][32][392];   // 50.2 KB
    __shared__ alignas(16) f16 h1B[2][32][136];     // 17.4 KB
    __shared__ int   s_src[3][32];
    __shared__ int   s_dst[3][32];
    __shared__ float s_sq[3][32];

    const int b = ((blockIdx.x & 7) << 7) | (blockIdx.x >> 3);
    const int t0 = (int)((long)b * NT_E / NB_E);
    const int t1 = (int)((long)(b + 1) * NT_E / NB_E);

    const int srow = tid >> 4, sch = tid & 15;
    const int sj = ((srow >> 2) & 3) * 8 + ((srow >> 4) << 2) + (srow & 3); // eperm

    // ---- prologue: meta(t0), meta(t0+1); stage Atile[t0&1] fully ----
    if (tid < 32) {
        int e0 = t0 * 32 + tid;
        s_src[t0 % 3][tid] = perm_src[e0];
        s_dst[t0 % 3][tid] = perm_dst[e0];
        s_sq [t0 % 3][tid] = perm_sq[e0];
        int e1 = min((t0 + 1) * 32 + tid, N_EDGES - 1);
        s_src[(t0 + 1) % 3][tid] = perm_src[e1];
        s_dst[(t0 + 1) % 3][tid] = perm_dst[e1];
        s_sq [(t0 + 1) % 3][tid] = perm_sq[e1];
    }
    __syncthreads();
    {
        const int pa = t0 & 1;
        int sv = s_src[t0 % 3][sj], dv = s_dst[t0 % 3][sj];
        int4 ra = ((const int4*)(fh + (size_t)sv * H))[sch];
        int4 rb = ((const int4*)(fh + (size_t)dv * H))[sch];
        ((int4*)&Atile[pa][srow][0])[sch]   = ra;
        ((int4*)&Atile[pa][srow][128])[sch] = rb;
        #pragma unroll
        for (int m = 0; m < 2; ++m) {
            f16x8 aa;
            if (lq < 2) {
                int j = (l16 >> 2) * 8 + m * 4 + (l16 & 3);
                aa = *(const f16x8*)(perm_ewh + (size_t)(t0 * 32 + j) * 16 + lq * 8);
            } else {
                #pragma unroll
                for (int jj = 0; jj < 8; ++jj) aa[jj] = (f16)0.0f;
            }
            f32x4 c = {bev, bev, bev, bev};
            c = __builtin_amdgcn_mfma_f32_16x16x32_f16(aa, wef, c, 0, 0, 0);
            #pragma unroll
            for (int r = 0; r < 4; ++r)
                Atile[pa][m * 16 + lq * 4 + r][256 + col] = (f16)fmaxf(c[r], 0.0f);
        }
    }
    __syncthreads();

    int dcp[8];
    for (int t = t0; t < t1; ++t) {
        const int pa = t & 1;
        const int m0 = t % 3;
        const int m1 = (t + 1) % 3;
        const int m2 = (t + 2) % 3;

        // 1. dc(t), acc1 init
        int dc[8];
        f32x4 acc1[2];
        #pragma unroll
        for (int m = 0; m < 2; ++m)
            #pragma unroll
            for (int r = 0; r < 4; ++r) {
                int j = lq * 8 + m * 4 + r;
                dc[m * 4 + r] = s_dst[m0][j];
                acc1[m][r] = fmaf(s_sq[m0][j], w1last, b1v);
            }

        // 2. issue loads for tile t+1 (clamped meta -> always valid ids)
        int4 rs_, rd_;
        f16x8 rew[2];
        {
            int sv = s_src[m1][sj], dv = s_dst[m1][sj];
            rs_ = ((const int4*)(fh + (size_t)sv * H))[sch];
            rd_ = ((const int4*)(fh + (size_t)dv * H))[sch];
            #pragma unroll
            for (int m = 0; m < 2; ++m) {
                if (lq < 2) {
                    int j = (l16 >> 2) * 8 + m * 4 + (l16 & 3);
                    int e = min((t + 1) * 32 + j, N_EDGES - 1);
                    rew[m] = *(const f16x8*)(perm_ewh + (size_t)e * 16 + lq * 8);
                }
            }
        }
        // 3. issue meta(t+2) loads
        int mrs = 0, mrd = 0; float mrq = 0.0f;
        if (tid < 32) {
            int e = min((t + 2) * 32 + tid, N_EDGES - 1);
            mrs = perm_src[e]; mrd = perm_dst[e]; mrq = perm_sq[e];
        }

        // 4+5. mm2(t-1) + atomic scatter (reads h1B[pa^1], dcp)
        if (t > t0) {
            f32x4 acc2[2];
            #pragma unroll
            for (int m = 0; m < 2; ++m) {
                f32x4 c = {b2v, b2v, b2v, b2v};
                acc2[m] = c;
            }
            #pragma unroll
            for (int k = 0; k < 4; ++k) {
                #pragma unroll
                for (int m = 0; m < 2; ++m) {
                    f16x8 a = *(const f16x8*)&h1B[pa ^ 1][m * 16 + l16][k * 32 + lq * 8];
                    acc2[m] = __builtin_amdgcn_mfma_f32_16x16x32_f16(a, w2f[k], acc2[m], 0, 0, 0);
                }
            }
            float run = fmaxf(acc2[0][0], 0.0f);
            int cd = dcp[0];
            #pragma unroll
            for (int i = 1; i < 8; ++i) {
                float v = fmaxf(acc2[i >> 2][i & 3], 0.0f);
                int d = dcp[i];
                if (d == cd) {
                    run += v;
                } else {
                    float nb = __shfl_xor(run, 1);
                    if ((l16 & 1) == 0) {
                        union { f16 h[2]; __half2 v2; } u;
                        u.h[0] = (f16)run; u.h[1] = (f16)nb;
                        unsafeAtomicAdd((__half2*)&msum[(size_t)cd * H + col], u.v2);
                    }
                    run = v; cd = d;
                }
            }
            float nb = __shfl_xor(run, 1);
            if ((l16 & 1) == 0) {
                union { f16 h[2]; __half2 v2; } u;
                u.h[0] = (f16)run; u.h[1] = (f16)nb;
                unsafeAtomicAdd((__half2*)&msum[(size_t)cd * H + col], u.v2);
            }
        }

        // 6. mm1(t) -> h1B[pa]
        #pragma unroll
        for (int k = 0; k < 12; ++k) {
            #pragma unroll
            for (int m = 0; m < 2; ++m) {
                f16x8 a = *(const f16x8*)&Atile[pa][m * 16 + l16][k * 32 + lq * 8];
                acc1[m] = __builtin_amdgcn_mfma_f32_16x16x32_f16(a, w1f[k], acc1[m], 0, 0, 0);
            }
        }
        #pragma unroll
        for (int m = 0; m < 2; ++m)
            #pragma unroll
            for (int r = 0; r < 4; ++r)
                h1B[pa][m * 16 + lq * 4 + r][col] = (f16)fmaxf(acc1[m][r], 0.0f);

        // 7. we-MFMA(t+1) -> Atile[pa^1] w cols
        #pragma unroll
        for (int m = 0; m < 2; ++m) {
            f16x8 aa;
            if (lq < 2) {
                aa = rew[m];
            } else {
                #pragma unroll
                for (int jj = 0; jj < 8; ++jj) aa[jj] = (f16)0.0f;
            }
            f32x4 c = {bev, bev, bev, bev};
            c = __builtin_amdgcn_mfma_f32_16x16x32_f16(aa, wef, c, 0, 0, 0);
            #pragma unroll
            for (int r = 0; r < 4; ++r)
                Atile[pa ^ 1][m * 16 + lq * 4 + r][256 + col] = (f16)fmaxf(c[r], 0.0f);
        }
        // 8. stage fs/fd(t+1) -> Atile[pa^1]
        ((int4*)&Atile[pa ^ 1][srow][0])[sch]   = rs_;
        ((int4*)&Atile[pa ^ 1][srow][128])[sch] = rd_;
        // 9. meta(t+2) -> LDS
        if (tid < 32) {
            s_src[m2][tid] = mrs; s_dst[m2][tid] = mrd; s_sq[m2][tid] = mrq;
        }
        // 10. carry dc
        #pragma unroll
        for (int i = 0; i < 8; ++i) dcp[i] = dc[i];
        __syncthreads();
    }

    // ---- epilogue: mm2(t1-1) + atomics ----
    {
        const int ph = (t1 - 1) & 1;
        f32x4 acc2[2];
        #pragma unroll
        for (int m = 0; m < 2; ++m) {
            f32x4 c = {b2v, b2v, b2v, b2v};
            acc2[m] = c;
        }
        #pragma unroll
        for (int k = 0; k < 4; ++k) {
            #pragma unroll
            for (int m = 0; m < 2; ++m) {
                f16x8 a = *(const f16x8*)&h1B[ph][m * 16 + l16][k * 32 + lq * 8];
                acc2[m] = __builtin_amdgcn_mfma_f32_16x16x32_f16(a, w2f[k], acc2[m], 0, 0, 0);
            }
        }
        float run = fmaxf(acc2[0][0], 0.0f);
        int cd = dcp[0];
        #pragma unroll
        for (int i = 1; i < 8; ++i) {
            float v = fmaxf(acc2[i >> 2][i & 3], 0.0f);
            int d = dcp[i];
            if (d == cd) {
                run += v;
            } else {
                float nb = __shfl_xor(run, 1);
                if ((l16 & 1) == 0) {
                    union { f16 h[2]; __half2 v2; } u;
                    u.h[0] = (f16)run; u.h[1] = (f16)nb;
                    unsafeAtomicAdd((__half2*)&msum[(size_t)cd * H + col], u.v2);
                }
                run = v; cd = d;
            }
        }
        float nb = __shfl_xor(run, 1);
        if ((l16 & 1) == 0) {
            union { f16 h[2]; __half2 v2; } u;
            u.h[0] = (f16)run; u.h[1] = (f16)nb;
            unsafeAtomicAdd((__half2*)&msum[(size_t)cd * H + col], u.v2);
        }
    }
}

// ---------------------------------------------------------------------------
// Node update: fh = relu(relu((msum+fh)@U1+b1)@U2+b2), pipelined, 2 barriers.
// ---------------------------------------------------------------------------
__global__ __launch_bounds__(256, 3) void k_update(
    const f16* __restrict__ msum, f16* __restrict__ fh,
    const float* __restrict__ W1, const float* __restrict__ b1,
    const float* __restrict__ W2, const float* __restrict__ b2)
{
    const int tid = threadIdx.x;
    const int wave = tid >> 6;       // 0..3
    const int lane = tid & 63;
    const int l16 = lane & 15;
    const int lq = lane >> 4;
    const int colbase = wave * 32;

    f16x8 w1fr[4][2], w2fr[4][2];
    float b1v[2], b2v[2];
    #pragma unroll
    for (int nt = 0; nt < 2; ++nt) {
        const int col = colbase + nt * 16 + l16;
        #pragma unroll
        for (int k = 0; k < 4; ++k) {
            f16x8 v1, v2;
            #pragma unroll
            for (int j = 0; j < 8; ++j) {
                v1[j] = (f16)W1[(size_t)(k * 32 + lq * 8 + j) * H + col];
                v2[j] = (f16)W2[(size_t)(k * 32 + lq * 8 + j) * H + col];
            }
            w1fr[k][nt] = v1;
            w2fr[k][nt] = v2;
        }
        b1v[nt] = b1[col];
        b2v[nt] = b2[col];
    }

    __shared__ alignas(16) f16 U[32][136];
    __shared__ alignas(16) f16 h1b[32][136];
    const int row = tid >> 3, ch = tid & 7;   // staging: 32 rows x 8 int4

    int tile = blockIdx.x;
    f16x8 rm0, rm1, rf0, rf1;
    if (tile < NT_N) {
        int n = min(tile * 32 + row, N_NODES - 1);
        const f16x8* pm = (const f16x8*)(msum + (size_t)n * H) + ch * 2;
        const f16x8* pf = (const f16x8*)(fh + (size_t)n * H) + ch * 2;
        rm0 = pm[0]; rm1 = pm[1]; rf0 = pf[0]; rf1 = pf[1];
    }
    for (; tile < NT_N; tile += gridDim.x) {
        const int n0 = tile * 32;
        {
            f16 tmp[16];
            #pragma unroll
            for (int j = 0; j < 8; ++j) {
                tmp[j]     = (f16)((float)rm0[j] + (float)rf0[j]);
                tmp[8 + j] = (f16)((float)rm1[j] + (float)rf1[j]);
            }
            int4* q0 = (int4*)(&U[row][ch * 16]);
            q0[0] = ((const int4*)tmp)[0];
            q0[1] = ((const int4*)tmp)[1];
        }
        {
            int nt_ = tile + gridDim.x;
            if (nt_ < NT_N) {
                int n = min(nt_ * 32 + row, N_NODES - 1);
                const f16x8* pm = (const f16x8*)(msum + (size_t)n * H) + ch * 2;
                const f16x8* pf = (const f16x8*)(fh + (size_t)n * H) + ch * 2;
                rm0 = pm[0]; rm1 = pm[1]; rf0 = pf[0]; rf1 = pf[1];
            }
        }
        __syncthreads();   // B1

        f32x4 acc[2][2];
        #pragma unroll
        for (int m = 0; m < 2; ++m)
            #pragma unroll
            for (int nt = 0; nt < 2; ++nt) {
                f32x4 c = {b1v[nt], b1v[nt], b1v[nt], b1v[nt]};
                acc[m][nt] = c;
            }
        #pragma unroll
        for (int k = 0; k < 4; ++k) {
            #pragma unroll
            for (int m = 0; m < 2; ++m) {
                f16x8 a = *(const f16x8*)&U[m * 16 + l16][k * 32 + lq * 8];
                #pragma unroll
                for (int nt = 0; nt < 2; ++nt)
                    acc[m][nt] = __builtin_amdgcn_mfma_f32_16x16x32_f16(a, w1fr[k][nt], acc[m][nt], 0, 0, 0);
            }
        }
        #pragma unroll
        for (int m = 0; m < 2; ++m)
            #pragma unroll
            for (int nt = 0; nt < 2; ++nt)
                #pragma unroll
                for (int r = 0; r < 4; ++r)
                    h1b[m * 16 + lq * 4 + r][colbase + nt * 16 + l16] = (f16)fmaxf(acc[m][nt][r], 0.0f);
        __syncthreads();   // B2

        f32x4 acc2[2][2];
        #pragma unroll
        for (int m = 0; m < 2; ++m)
            #pragma unroll
            for (int nt = 0; nt < 2; ++nt) {
                f32x4 c = {b2v[nt], b2v[nt], b2v[nt], b2v[nt]};
                acc2[m][nt] = c;
            }
        #pragma unroll
        for (int k = 0; k < 4; ++k) {
            #pragma unroll
            for (int m = 0; m < 2; ++m) {
                f16x8 a = *(const f16x8*)&h1b[m * 16 + l16][k * 32 + lq * 8];
                #pragma unroll
                for (int nt = 0; nt < 2; ++nt)
                    acc2[m][nt] = __builtin_amdgcn_mfma_f32_16x16x32_f16(a, w2fr[k][nt], acc2[m][nt], 0, 0, 0);
            }
        }
        #pragma unroll
        for (int m = 0; m < 2; ++m)
            #pragma unroll
            for (int nt = 0; nt < 2; ++nt)
                #pragma unroll
                for (int r = 0; r < 4; ++r) {
                    int rr = m * 16 + lq * 4 + r;
                    int n = n0 + rr;
                    if (n < N_NODES)
                        fh[(size_t)n * H + colbase + nt * 16 + l16] = (f16)fmaxf(acc2[m][nt][r], 0.0f);
                }
    }
}

// ---------------------------------------------------------------------------
// Per-graph mean/max readout (graph_ids sorted; f >= 0)
// ---------------------------------------------------------------------------
__global__ void k_readout(const f16* __restrict__ fh, const int* __restrict__ gid,
                          float* __restrict__ gsum, float* __restrict__ gmax,
                          int* __restrict__ gcnt)
{
    __shared__ int s_gid[64];
    const int tid = threadIdx.x;            // 128 threads
    const int base = blockIdx.x * 64;
    if (tid < 64) s_gid[tid] = (base + tid < N_NODES) ? gid[base + tid] : -1;
    __syncthreads();
    if (tid < 64 && base + tid < N_NODES) atomicAdd(&gcnt[s_gid[tid]], 1);

    float lsum = 0.0f, lmax = 0.0f;
    int cur = s_gid[0];
    if (cur >= 0) {
        for (int i = 0; i < 64; ++i) {
            int g = s_gid[i];
            if (g < 0) break;
            if (g != cur) {
                unsafeAtomicAdd(&gsum[(size_t)cur * H + tid], lsum);
                atomicMax((int*)&gmax[(size_t)cur * H + tid], __float_as_int(lmax));
                lsum = 0.0f; lmax = 0.0f; cur = g;
            }
            float v = (float)fh[(size_t)(base + i) * H + tid];
            lsum += v;
            lmax = fmaxf(lmax, v);
        }
        unsafeAtomicAdd(&gsum[(size_t)cur * H + tid], lsum);
        atomicMax((int*)&gmax[(size_t)cur * H + tid], __float_as_int(lmax));
    }
}

__global__ void k_out(const float* __restrict__ gsum, const float* __restrict__ gmax,
                      const int* __restrict__ gcnt, const float* __restrict__ W_out,
                      const float* __restrict__ b_out, float* __restrict__ out)
{
    __shared__ float sm[128], sx[128];
    const int g = blockIdx.x, t = threadIdx.x;
    const float inv = 1.0f / fmaxf((float)gcnt[g], 1.0f);
    sm[t] = gsum[(size_t)g * H + t] * inv;
    sx[t] = gmax[(size_t)g * H + t];
    __syncthreads();
    float acc = b_out[t];
    for (int k = 0; k < H; ++k) {
        acc = fmaf(sm[k], W_out[(size_t)k * 128 + t], acc);
        acc = fmaf(sx[k], W_out[(size_t)(128 + k) * 128 + t], acc);
    }
    out[(size_t)g * 128 + t] = acc;
}

// ---------------------------------------------------------------------------
extern "C" void kernel_launch(void* const* d_in, const int* in_sizes, int n_in,
                              void* d_out, int out_size, void* d_ws, size_t ws_size,
                              hipStream_t stream)
{
    const float* node_f = (const float*)d_in[0];
    const float* node_x = (const float*)d_in[1];
    const float* edge_w = (const float*)d_in[2];
    const int*   src    = (const int*)d_in[3];
    const int*   dst    = (const int*)d_in[4];
    const int*   gid    = (const int*)d_in[5];
    const float* W_in   = (const float*)d_in[6];
    const float* b_in   = (const float*)d_in[7];
    const float* W_e    = (const float*)d_in[8];
    const float* b_e    = (const float*)d_in[9];
    const float* msg_W1 = (const float*)d_in[10];
    const float* msg_b1 = (const float*)d_in[11];
    const float* msg_W2 = (const float*)d_in[12];
    const float* msg_b2 = (const float*)d_in[13];
    const float* upd_W1 = (const float*)d_in[14];
    const float* upd_b1 = (const float*)d_in[15];
    const float* upd_W2 = (const float*)d_in[16];
    const float* upd_b2 = (const float*)d_in[17];
    const float* W_out  = (const float*)d_in[18];
    const float* b_out  = (const float*)d_in[19];
    float* out = (float*)d_out;

    char* ws = (char*)d_ws;
    size_t off = 0;
    f16*   fh       = (f16*)(ws + off);   off += (size_t)N_NODES * H * 2;      // 12.8 MB
    f16*   perm_ewh = (f16*)(ws + off);   off += (size_t)N_EDGES * 16 * 2;     // 19.2 MB
    int*   perm_src = (int*)(ws + off);   off += (size_t)N_EDGES * 4;          // 2.4 MB
    int*   perm_dst = (int*)(ws + off);   off += (size_t)N_EDGES * 4;          // 2.4 MB
    float* perm_sq  = (float*)(ws + off); off += (size_t)N_EDGES * 4;          // 2.4 MB
    int*   rowptr   = (int*)(ws + off);   off += (size_t)NP * 4;
    int*   cnt      = (int*)(ws + off);   off += (size_t)NP * 4;               // also 'fill'
    int*   bsum     = (int*)(ws + off);   off += 256 * 4;
    int*   boff     = (int*)(ws + off);   off += 256 * 4;
    f16*   msum     = (f16*)(ws + off);   off += (size_t)N_NODES * H * 2;      // 12.8 MB
    float* gsum     = (float*)(ws + off); off += (size_t)G_GRAPHS * H * 4;
    float* gmax     = (float*)(ws + off); off += (size_t)G_GRAPHS * H * 4;
    int*   gcnt     = (int*)(ws + off);   off += (size_t)G_GRAPHS * 4;
    int*   perm_eidx = (int*)msum;        // aliased: eidx only used pre-layers

    k_f0<<<(N_NODES + 7) / 8, 128, 0, stream>>>(node_f, W_in, b_in, fh);

    (void)hipMemsetAsync(cnt, 0, (size_t)NP * 4, stream);
    k_hist<<<(N_EDGES + 255) / 256, 256, 0, stream>>>(dst, cnt);
    k_scanA<<<NP / 256, 256, 0, stream>>>(cnt, rowptr, bsum);
    k_scanB<<<1, 256, 0, stream>>>(bsum, boff);
    k_scanC<<<NP / 256, 256, 0, stream>>>(rowptr, boff);
    (void)hipMemsetAsync(cnt, 0, (size_t)NP * 4, stream);
    k_scatter_idx<<<(N_EDGES + 255) / 256, 256, 0, stream>>>(dst, rowptr, cnt, perm_eidx);
    k_gather<<<(N_EDGES + 255) / 256, 256, 0, stream>>>(perm_eidx, edge_w, src, dst, node_x,
                                                        perm_src, perm_dst, perm_sq, perm_ewh);

    for (int l = 0; l < 4; ++l) {
        (void)hipMemsetAsync(msum, 0, (size_t)N_NODES * H * 2, stream);
        k_edge2<<<NB_E, 512, 0, stream>>>(fh, perm_src, perm_dst, perm_sq, perm_ewh,
                                          W_e, b_e,
                                          msg_W1 + (size_t)l * 385 * H, msg_b1 + (size_t)l * H,
                                          msg_W2 + (size_t)l * H * H,  msg_b2 + (size_t)l * H,
                                          msum);
        k_update<<<512, 256, 0, stream>>>(msum, fh,
                                          upd_W1 + (size_t)l * H * H, upd_b1 + (size_t)l * H,
                                          upd_W2 + (size_t)l * H * H, upd_b2 + (size_t)l * H);
    }

    (void)hipMemsetAsync(gsum, 0, (size_t)G_GRAPHS * H * 4, stream);
    (void)hipMemsetAsync(gmax, 0, (size_t)G_GRAPHS * H * 4, stream);
    (void)hipMemsetAsync(gcnt, 0, (size_t)G_GRAPHS * 4, stream);
    k_readout<<<(N_NODES + 63) / 64, 128, 0, stream>>>(fh, gid, gsum, gmax, gcnt);
    k_out<<<G_GRAPHS, 128, 0, stream>>>(gsum, gmax, gcnt, W_out, b_out, out);
}